// Round 1
// baseline (524.625 us; speedup 1.0000x reference)
//
#include <hip/hip_runtime.h>
#include <hip/hip_bf16.h>

// ---------------------------------------------------------------------------
// GCN link-prediction pipeline, fp32:
//   h0 = x @ W_init + b_init
//   h1 = relu(gcn_conv(h0, W1, b1))
//   h2 = gcn_conv(h1, W2, b2)
//   logits[e] = dot(h2[ea[e]], h2[eb[e]])
// gcn_conv(x,W,b) = segsum_tgt(xw[src]*dinv[src]*dinv[tgt]) + xw*dinv^2 + b
// ---------------------------------------------------------------------------

__global__ void deg_init_kernel(float* __restrict__ deg, int n) {
    int i = blockIdx.x * blockDim.x + threadIdx.x;
    if (i < n) deg[i] = 1.0f;   // self-loop
}

__global__ void deg_count_kernel(const int* __restrict__ tgt, float* __restrict__ deg, int e) {
    int i = blockIdx.x * blockDim.x + threadIdx.x;
    if (i < e) atomicAdd(&deg[tgt[i]], 1.0f);
}

__global__ void dinv_kernel(float* __restrict__ deg, int n) {
    int i = blockIdx.x * blockDim.x + threadIdx.x;
    if (i < n) deg[i] = 1.0f / sqrtf(deg[i]);
}

// ---------------------------------------------------------------------------
// Register-tiled fp32 GEMM, K fixed at 128. A: M x 128 row-major.
// B: 128 x BN row-major. C: M x BN. 256 threads, BM=128 rows per block.
// Per-thread tile TM=8 x TN (8 for BN=128, 4 for BN=64).
// ---------------------------------------------------------------------------
template<int BN, int TN, bool RELU_IN, bool ADD_BIAS>
__global__ __launch_bounds__(256)
void gemm128_kernel(const float* __restrict__ A, const float* __restrict__ B,
                    const float* __restrict__ bias, float* __restrict__ C, int M)
{
    constexpr int K  = 128;
    constexpr int BM = 128;
    constexpr int BK = 32;
    constexpr int TM = 8;

    __shared__ float As[BK][BM];   // transposed: As[k][m]
    __shared__ float Bs[BK][BN];   // Bs[k][n]

    const int tid = threadIdx.x;
    const int tx = tid & 15;       // 16 col-groups
    const int ty = tid >> 4;       // 16 row-groups
    const long long row0 = (long long)blockIdx.x * BM;

    float acc[TM][TN];
#pragma unroll
    for (int i = 0; i < TM; i++)
#pragma unroll
        for (int j = 0; j < TN; j++) acc[i][j] = 0.0f;

    for (int kk = 0; kk < K; kk += BK) {
        // ---- A tile: 128 rows x 32 k. thread -> row = tid>>1, kbase = (tid&1)*16
        {
            const int r  = tid >> 1;
            const int kb = (tid & 1) << 4;
            const long long gr = row0 + r;
            float4 v[4];
            if (gr < M) {
                const float4* p = (const float4*)(A + gr * K + kk + kb);
#pragma unroll
                for (int i = 0; i < 4; i++) v[i] = p[i];
            } else {
#pragma unroll
                for (int i = 0; i < 4; i++) v[i] = make_float4(0.f, 0.f, 0.f, 0.f);
            }
            if (RELU_IN) {
#pragma unroll
                for (int i = 0; i < 4; i++) {
                    v[i].x = fmaxf(v[i].x, 0.f); v[i].y = fmaxf(v[i].y, 0.f);
                    v[i].z = fmaxf(v[i].z, 0.f); v[i].w = fmaxf(v[i].w, 0.f);
                }
            }
#pragma unroll
            for (int i = 0; i < 4; i++) {
                As[kb + 4*i + 0][r] = v[i].x;
                As[kb + 4*i + 1][r] = v[i].y;
                As[kb + 4*i + 2][r] = v[i].z;
                As[kb + 4*i + 3][r] = v[i].w;
            }
        }
        // ---- B tile: 32 k x BN floats, contiguous in global.
        {
            constexpr int F4_PER_THREAD = (BK * BN) / (256 * 4);
#pragma unroll
            for (int i = 0; i < F4_PER_THREAD; i++) {
                const int f4 = tid * F4_PER_THREAD + i;
                const int kr = (f4 * 4) / BN;
                const int nc = (f4 * 4) % BN;
                *(float4*)&Bs[kr][nc] = *(const float4*)(B + (long long)(kk + kr) * BN + nc);
            }
        }
        __syncthreads();

#pragma unroll
        for (int k = 0; k < BK; k++) {
            float a[TM], b[TN];
            *(float4*)&a[0] = *(const float4*)&As[k][ty * TM + 0];
            *(float4*)&a[4] = *(const float4*)&As[k][ty * TM + 4];
#pragma unroll
            for (int j = 0; j < TN; j += 4)
                *(float4*)&b[j] = *(const float4*)&Bs[k][tx * TN + j];
#pragma unroll
            for (int i = 0; i < TM; i++)
#pragma unroll
                for (int j = 0; j < TN; j++)
                    acc[i][j] = fmaf(a[i], b[j], acc[i][j]);
        }
        __syncthreads();
    }

    // ---- store
#pragma unroll
    for (int i = 0; i < TM; i++) {
        const long long gr = row0 + ty * TM + i;
        if (gr < M) {
#pragma unroll
            for (int j = 0; j < TN; j += 4) {
                float4 v = make_float4(acc[i][j], acc[i][j+1], acc[i][j+2], acc[i][j+3]);
                if (ADD_BIAS) {
                    v.x += bias[tx*TN + j + 0]; v.y += bias[tx*TN + j + 1];
                    v.z += bias[tx*TN + j + 2]; v.w += bias[tx*TN + j + 3];
                }
                *(float4*)(C + gr * BN + tx * TN + j) = v;
            }
        }
    }
}

// ---------------------------------------------------------------------------
// out[i][d] = xw[i][d] * dinv[i]^2 + bias[d]   (self-loop term + bias)
// ---------------------------------------------------------------------------
template<int D>
__global__ void self_init_kernel(const float* __restrict__ xw, const float* __restrict__ dinv,
                                 const float* __restrict__ bias, float* __restrict__ out,
                                 int n)
{
    long long i4 = (long long)blockIdx.x * blockDim.x + threadIdx.x;
    long long total4 = (long long)n * D / 4;
    if (i4 >= total4) return;
    long long e = i4 * 4;
    int node = (int)(e / D);
    int d = (int)(e % D);
    float di = dinv[node];
    float c = di * di;
    float4 v = *(const float4*)(xw + e);
    float4 r;
    r.x = v.x * c + bias[d + 0];
    r.y = v.y * c + bias[d + 1];
    r.z = v.z * c + bias[d + 2];
    r.w = v.w * c + bias[d + 3];
    *(float4*)(out + e) = r;
}

// ---------------------------------------------------------------------------
// Edge scatter: out[tgt] += xw[src] * dinv[src]*dinv[tgt].  1 wave per edge.
// ---------------------------------------------------------------------------
template<int D>
__global__ void edge_agg_kernel(const float* __restrict__ xw, const float* __restrict__ dinv,
                                const int* __restrict__ src, const int* __restrict__ tgt,
                                float* __restrict__ out, int E)
{
    int wid = (int)(((long long)blockIdx.x * blockDim.x + threadIdx.x) >> 6);
    int lane = threadIdx.x & 63;
    if (wid >= E) return;
    int s = src[wid], t = tgt[wid];
    float nrm = dinv[s] * dinv[t];
    const float* xs = xw + (long long)s * D;
    float* ot = out + (long long)t * D;
#pragma unroll
    for (int d = lane; d < D; d += 64)
        atomicAdd(&ot[d], xs[d] * nrm);
}

// ---------------------------------------------------------------------------
// logits[e] = dot(h[a], h[b]) over D=64. 16 lanes per edge, float4 each.
// ---------------------------------------------------------------------------
__global__ void score_kernel(const float* __restrict__ h, const int* __restrict__ ea,
                             const int* __restrict__ eb, float* __restrict__ out, int E)
{
    long long gid = (long long)blockIdx.x * blockDim.x + threadIdx.x;
    int e = (int)(gid >> 4);
    int l = (int)(gid & 15);
    if (e >= E) return;
    int a = ea[e], b = eb[e];
    float4 va = *(const float4*)(h + (long long)a * 64 + l * 4);
    float4 vb = *(const float4*)(h + (long long)b * 64 + l * 4);
    float s = va.x*vb.x + va.y*vb.y + va.z*vb.z + va.w*vb.w;
    s += __shfl_xor(s, 8);
    s += __shfl_xor(s, 4);
    s += __shfl_xor(s, 2);
    s += __shfl_xor(s, 1);
    if (l == 0) out[e] = s;
}

extern "C" void kernel_launch(void* const* d_in, const int* in_sizes, int n_in,
                              void* d_out, int out_size, void* d_ws, size_t ws_size,
                              hipStream_t stream)
{
    const float* x              = (const float*)d_in[0];
    const int*   edge_index     = (const int*)d_in[1];
    const int*   pos_edge_index = (const int*)d_in[2];
    const float* W_init         = (const float*)d_in[3];
    const float* b_init         = (const float*)d_in[4];
    const float* W1             = (const float*)d_in[5];
    const float* b1             = (const float*)d_in[6];
    const float* W2             = (const float*)d_in[7];
    const float* b2             = (const float*)d_in[8];
    float* out = (float*)d_out;

    const int N     = in_sizes[0] / 128;   // 100000
    const int Epred = in_sizes[1] / 2;     // 200000
    const int E     = in_sizes[2] / 2;     // 500000

    const int* src = pos_edge_index;
    const int* tgt = pos_edge_index + E;
    const int* ea  = edge_index;
    const int* eb  = edge_index + Epred;

    float* bufA = (float*)d_ws;                    // N*128 (h0 -> out1 -> out2)
    float* bufB = bufA + (size_t)N * 128;          // N*128 (xw1 -> xw2)
    float* dinv = bufB + (size_t)N * 128;          // N     (deg -> dinv)

    const int BLK = 256;

    // --- degree / dinv ---
    deg_init_kernel<<<(N + BLK - 1) / BLK, BLK, 0, stream>>>(dinv, N);
    deg_count_kernel<<<(E + BLK - 1) / BLK, BLK, 0, stream>>>(tgt, dinv, E);
    dinv_kernel<<<(N + BLK - 1) / BLK, BLK, 0, stream>>>(dinv, N);

    const int gemm_grid = (N + 127) / 128;

    // --- h0 = x @ W_init + b_init ---
    gemm128_kernel<128, 8, false, true><<<gemm_grid, BLK, 0, stream>>>(x, W_init, b_init, bufA, N);

    // --- conv1: xw1 = h0 @ W1 ---
    gemm128_kernel<128, 8, false, false><<<gemm_grid, BLK, 0, stream>>>(bufA, W1, nullptr, bufB, N);
    // out1 = xw1*dinv^2 + b1  (into bufA)
    self_init_kernel<128><<<((long long)N * 128 / 4 + BLK - 1) / BLK, BLK, 0, stream>>>(bufB, dinv, b1, bufA, N);
    // out1 += scatter(xw1[src]*norm)
    edge_agg_kernel<128><<<(E + 3) / 4, BLK, 0, stream>>>(bufB, dinv, src, tgt, bufA, E);

    // --- conv2: xw2 = relu(out1) @ W2 ---
    gemm128_kernel<64, 4, true, false><<<gemm_grid, BLK, 0, stream>>>(bufA, W2, nullptr, bufB, N);
    // out2 = xw2*dinv^2 + b2  (into bufA, N x 64)
    self_init_kernel<64><<<((long long)N * 64 / 4 + BLK - 1) / BLK, BLK, 0, stream>>>(bufB, dinv, b2, bufA, N);
    edge_agg_kernel<64><<<(E + 3) / 4, BLK, 0, stream>>>(bufB, dinv, src, tgt, bufA, E);

    // --- scoring ---
    score_kernel<<<((long long)Epred * 16 + BLK - 1) / BLK, BLK, 0, stream>>>(bufA, ea, eb, out, Epred);
}

// Round 2
// 338.205 us; speedup vs baseline: 1.5512x; 1.5512x over previous
//
#include <hip/hip_runtime.h>
#include <hip/hip_bf16.h>

// ---------------------------------------------------------------------------
// GCN link-prediction pipeline, fp32, CSR-gather version (no fp32 atomics):
//   h0 = x @ W_init + b_init
//   h1 = relu(gcn_conv(h0, W1, b1))
//   h2 = gcn_conv(h1, W2, b2)
//   logits[e] = dot(h2[ea[e]], h2[eb[e]])
// gcn_conv(x,W,b) = gather_tgt(xw[src]*dinv[src]*dinv[tgt]) + xw*dinv^2 + b
// CSR built on-device once (both convs share the graph).
// ---------------------------------------------------------------------------

__global__ void zero_ints_kernel(int* __restrict__ p, int n) {
    int i = blockIdx.x * blockDim.x + threadIdx.x;
    if (i < n) p[i] = 0;
}

__global__ void hist_kernel(const int* __restrict__ tgt, int* __restrict__ counts, int e) {
    int i = blockIdx.x * blockDim.x + threadIdx.x;
    if (i < e) atomicAdd(&counts[tgt[i]], 1);
}

__global__ void dinv_kernel(const int* __restrict__ counts, float* __restrict__ dinv, int n) {
    int i = blockIdx.x * blockDim.x + threadIdx.x;
    if (i < n) dinv[i] = 1.0f / sqrtf((float)(counts[i] + 1));  // +1 self-loop
}

// ---- exclusive scan of counts -> rowptr (1024 elems/block, 256 thr x 4) ----
__global__ __launch_bounds__(256)
void scan1_kernel(const int* __restrict__ counts, int* __restrict__ rowptr,
                  int* __restrict__ bsum, int n)
{
    __shared__ int sdata[256];
    const int t = threadIdx.x;
    const int base = blockIdx.x * 1024 + t * 4;
    int v[4];
#pragma unroll
    for (int i = 0; i < 4; i++) v[i] = (base + i < n) ? counts[base + i] : 0;
    int tsum = v[0] + v[1] + v[2] + v[3];
    sdata[t] = tsum;
    __syncthreads();
    for (int off = 1; off < 256; off <<= 1) {
        int x = (t >= off) ? sdata[t - off] : 0;
        __syncthreads();
        if (t >= off) sdata[t] += x;
        __syncthreads();
    }
    if (t == 255) bsum[blockIdx.x] = sdata[255];
    int run = sdata[t] - tsum;   // exclusive
#pragma unroll
    for (int i = 0; i < 4; i++) {
        if (base + i < n) rowptr[base + i] = run;
        run += v[i];
    }
}

__global__ __launch_bounds__(256)
void scan2_kernel(int* __restrict__ bsum, int nb)
{
    __shared__ int sdata[256];
    const int t = threadIdx.x;
    int v = (t < nb) ? bsum[t] : 0;
    sdata[t] = v;
    __syncthreads();
    for (int off = 1; off < 256; off <<= 1) {
        int x = (t >= off) ? sdata[t - off] : 0;
        __syncthreads();
        if (t >= off) sdata[t] += x;
        __syncthreads();
    }
    if (t < nb) bsum[t] = sdata[t] - v;   // exclusive
}

__global__ void scan3_kernel(int* __restrict__ rowptr, const int* __restrict__ bsum,
                             int n, int e_total)
{
    int i = blockIdx.x * blockDim.x + threadIdx.x;
    if (i < n) rowptr[i] += bsum[i >> 10];
    if (i == 0) rowptr[n] = e_total;
}

// ---- scatter edges into CSR slots: ew[p] = (src, dinv[src]*dinv[tgt]) ----
__global__ void scatter_kernel(const int* __restrict__ src, const int* __restrict__ tgt,
                               const float* __restrict__ dinv, const int* __restrict__ rowptr,
                               int* __restrict__ cursor, int2* __restrict__ ew, int e)
{
    int i = blockIdx.x * blockDim.x + threadIdx.x;
    if (i >= e) return;
    int s = src[i], t = tgt[i];
    int p = rowptr[t] + atomicAdd(&cursor[t], 1);
    float w = dinv[s] * dinv[t];
    ew[p] = make_int2(s, __float_as_int(w));
}

// ---------------------------------------------------------------------------
// Register-tiled fp32 GEMM, K fixed at 128 (unchanged from R1 — passed).
// ---------------------------------------------------------------------------
template<int BN, int TN, bool RELU_IN, bool ADD_BIAS>
__global__ __launch_bounds__(256)
void gemm128_kernel(const float* __restrict__ A, const float* __restrict__ B,
                    const float* __restrict__ bias, float* __restrict__ C, int M)
{
    constexpr int K  = 128;
    constexpr int BM = 128;
    constexpr int BK = 32;
    constexpr int TM = 8;

    __shared__ float As[BK][BM];
    __shared__ float Bs[BK][BN];

    const int tid = threadIdx.x;
    const int tx = tid & 15;
    const int ty = tid >> 4;
    const long long row0 = (long long)blockIdx.x * BM;

    float acc[TM][TN];
#pragma unroll
    for (int i = 0; i < TM; i++)
#pragma unroll
        for (int j = 0; j < TN; j++) acc[i][j] = 0.0f;

    for (int kk = 0; kk < K; kk += BK) {
        {
            const int r  = tid >> 1;
            const int kb = (tid & 1) << 4;
            const long long gr = row0 + r;
            float4 v[4];
            if (gr < M) {
                const float4* p = (const float4*)(A + gr * K + kk + kb);
#pragma unroll
                for (int i = 0; i < 4; i++) v[i] = p[i];
            } else {
#pragma unroll
                for (int i = 0; i < 4; i++) v[i] = make_float4(0.f, 0.f, 0.f, 0.f);
            }
            if (RELU_IN) {
#pragma unroll
                for (int i = 0; i < 4; i++) {
                    v[i].x = fmaxf(v[i].x, 0.f); v[i].y = fmaxf(v[i].y, 0.f);
                    v[i].z = fmaxf(v[i].z, 0.f); v[i].w = fmaxf(v[i].w, 0.f);
                }
            }
#pragma unroll
            for (int i = 0; i < 4; i++) {
                As[kb + 4*i + 0][r] = v[i].x;
                As[kb + 4*i + 1][r] = v[i].y;
                As[kb + 4*i + 2][r] = v[i].z;
                As[kb + 4*i + 3][r] = v[i].w;
            }
        }
        {
            constexpr int F4_PER_THREAD = (BK * BN) / (256 * 4);
#pragma unroll
            for (int i = 0; i < F4_PER_THREAD; i++) {
                const int f4 = tid * F4_PER_THREAD + i;
                const int kr = (f4 * 4) / BN;
                const int nc = (f4 * 4) % BN;
                *(float4*)&Bs[kr][nc] = *(const float4*)(B + (long long)(kk + kr) * BN + nc);
            }
        }
        __syncthreads();

#pragma unroll
        for (int k = 0; k < BK; k++) {
            float a[TM], b[TN];
            *(float4*)&a[0] = *(const float4*)&As[k][ty * TM + 0];
            *(float4*)&a[4] = *(const float4*)&As[k][ty * TM + 4];
#pragma unroll
            for (int j = 0; j < TN; j += 4)
                *(float4*)&b[j] = *(const float4*)&Bs[k][tx * TN + j];
#pragma unroll
            for (int i = 0; i < TM; i++)
#pragma unroll
                for (int j = 0; j < TN; j++)
                    acc[i][j] = fmaf(a[i], b[j], acc[i][j]);
        }
        __syncthreads();
    }

#pragma unroll
    for (int i = 0; i < TM; i++) {
        const long long gr = row0 + ty * TM + i;
        if (gr < M) {
#pragma unroll
            for (int j = 0; j < TN; j += 4) {
                float4 v = make_float4(acc[i][j], acc[i][j+1], acc[i][j+2], acc[i][j+3]);
                if (ADD_BIAS) {
                    v.x += bias[tx*TN + j + 0]; v.y += bias[tx*TN + j + 1];
                    v.z += bias[tx*TN + j + 2]; v.w += bias[tx*TN + j + 3];
                }
                *(float4*)(C + gr * BN + tx * TN + j) = v;
            }
        }
    }
}

// ---------------------------------------------------------------------------
// Per-node CSR gather + self-loop + bias. One wave per node.
//   out[t] = sum_j xw[col[j]] * w[j]  +  xw[t]*dinv[t]^2 + bias
// ---------------------------------------------------------------------------
template<int D>
__global__ __launch_bounds__(256)
void gather_conv_kernel(const float* __restrict__ xw, const float* __restrict__ dinv,
                        const int* __restrict__ rowptr, const int2* __restrict__ ew,
                        const float* __restrict__ bias, float* __restrict__ out, int n)
{
    const int node = blockIdx.x * (blockDim.x >> 6) + (threadIdx.x >> 6);
    const int lane = threadIdx.x & 63;
    if (node >= n) return;
    const float dt = dinv[node];
    const int j0 = rowptr[node], j1 = rowptr[node + 1];

    if (D == 128) {
        const float2 a  = ((const float2*)(xw + (long long)node * 128))[lane];
        const float2 bb = ((const float2*)bias)[lane];
        const float c = dt * dt;
        float accx = fmaf(a.x, c, bb.x);
        float accy = fmaf(a.y, c, bb.y);
        for (int j = j0; j < j1; ++j) {
            const int2 p = ew[j];
            const float w = __int_as_float(p.y);
            const float2 v = ((const float2*)(xw + (long long)p.x * 128))[lane];
            accx = fmaf(v.x, w, accx);
            accy = fmaf(v.y, w, accy);
        }
        ((float2*)(out + (long long)node * 128))[lane] = make_float2(accx, accy);
    } else {
        const float a = xw[(long long)node * 64 + lane];
        float acc = fmaf(a, dt * dt, bias[lane]);
        for (int j = j0; j < j1; ++j) {
            const int2 p = ew[j];
            const float w = __int_as_float(p.y);
            acc = fmaf(xw[(long long)p.x * 64 + lane], w, acc);
        }
        out[(long long)node * 64 + lane] = acc;
    }
}

// ---------------------------------------------------------------------------
// logits[e] = dot(h[a], h[b]) over D=64. 16 lanes per edge, float4 each.
// ---------------------------------------------------------------------------
__global__ void score_kernel(const float* __restrict__ h, const int* __restrict__ ea,
                             const int* __restrict__ eb, float* __restrict__ out, int E)
{
    long long gid = (long long)blockIdx.x * blockDim.x + threadIdx.x;
    int e = (int)(gid >> 4);
    int l = (int)(gid & 15);
    if (e >= E) return;
    int a = ea[e], b = eb[e];
    float4 va = *(const float4*)(h + (long long)a * 64 + l * 4);
    float4 vb = *(const float4*)(h + (long long)b * 64 + l * 4);
    float s = va.x*vb.x + va.y*vb.y + va.z*vb.z + va.w*vb.w;
    s += __shfl_xor(s, 8);
    s += __shfl_xor(s, 4);
    s += __shfl_xor(s, 2);
    s += __shfl_xor(s, 1);
    if (l == 0) out[e] = s;
}

extern "C" void kernel_launch(void* const* d_in, const int* in_sizes, int n_in,
                              void* d_out, int out_size, void* d_ws, size_t ws_size,
                              hipStream_t stream)
{
    const float* x              = (const float*)d_in[0];
    const int*   edge_index     = (const int*)d_in[1];
    const int*   pos_edge_index = (const int*)d_in[2];
    const float* W_init         = (const float*)d_in[3];
    const float* b_init         = (const float*)d_in[4];
    const float* W1             = (const float*)d_in[5];
    const float* b1             = (const float*)d_in[6];
    const float* W2             = (const float*)d_in[7];
    const float* b2             = (const float*)d_in[8];
    float* out = (float*)d_out;

    const int N     = in_sizes[0] / 128;   // 100000
    const int Epred = in_sizes[1] / 2;     // 200000
    const int E     = in_sizes[2] / 2;     // 500000

    const int* src = pos_edge_index;
    const int* tgt = pos_edge_index + E;
    const int* ea  = edge_index;
    const int* eb  = edge_index + Epred;

    // ---- workspace layout (8B-aligned first) ----
    int2*  ew     = (int2*)d_ws;                       // E
    float* bufA   = (float*)(ew + E);                  // N*128
    float* bufB   = bufA + (size_t)N * 128;            // N*128
    float* dinv   = bufB + (size_t)N * 128;            // N
    int*   counts = (int*)(dinv + N);                  // N
    int*   cursor = counts + N;                        // N   (contiguous with counts)
    int*   rowptr = cursor + N;                        // N+2
    int*   bsum   = rowptr + N + 2;                    // 256

    const int BLK = 256;
    const int nb  = (N + 1023) / 1024;

    // ---- CSR build (once; shared by both convs) ----
    zero_ints_kernel<<<(2 * N + BLK - 1) / BLK, BLK, 0, stream>>>(counts, 2 * N);
    hist_kernel<<<(E + BLK - 1) / BLK, BLK, 0, stream>>>(tgt, counts, E);
    dinv_kernel<<<(N + BLK - 1) / BLK, BLK, 0, stream>>>(counts, dinv, N);
    scan1_kernel<<<nb, 256, 0, stream>>>(counts, rowptr, bsum, N);
    scan2_kernel<<<1, 256, 0, stream>>>(bsum, nb);
    scan3_kernel<<<(N + BLK - 1) / BLK, BLK, 0, stream>>>(rowptr, bsum, N, E);
    scatter_kernel<<<(E + BLK - 1) / BLK, BLK, 0, stream>>>(src, tgt, dinv, rowptr, cursor, ew, E);

    const int gemm_grid = (N + 127) / 128;

    // ---- h0 = x @ W_init + b_init ----
    gemm128_kernel<128, 8, false, true><<<gemm_grid, BLK, 0, stream>>>(x, W_init, b_init, bufA, N);

    // ---- conv1 ----
    gemm128_kernel<128, 8, false, false><<<gemm_grid, BLK, 0, stream>>>(bufA, W1, nullptr, bufB, N);
    gather_conv_kernel<128><<<(N + 3) / 4, BLK, 0, stream>>>(bufB, dinv, rowptr, ew, b1, bufA, N);

    // ---- conv2 (relu fused into GEMM A-load) ----
    gemm128_kernel<64, 4, true, false><<<gemm_grid, BLK, 0, stream>>>(bufA, W2, nullptr, bufB, N);
    gather_conv_kernel<64><<<(N + 3) / 4, BLK, 0, stream>>>(bufB, dinv, rowptr, ew, b2, bufA, N);

    // ---- scoring ----
    score_kernel<<<((long long)Epred * 16 + BLK - 1) / BLK, BLK, 0, stream>>>(bufA, ea, eb, out, Epred);
}

// Round 3
// 248.401 us; speedup vs baseline: 2.1120x; 1.3615x over previous
//
#include <hip/hip_runtime.h>

// ---------------------------------------------------------------------------
// GCN link-prediction pipeline. GEMMs via split-bf16 MFMA (near-fp32 accuracy),
// graph aggregation via CSR gather on bf16 operands (fp32 accumulate).
//   h0  = x @ W_init + b_init                       (fp32, bufB)
//   xw1 = bf16(h0 @ W1)                             (in-place over bufB rows)
//   out1= gather(xw1) + self + b1                   (fp32, bufA)
//   xw2 = bf16(relu(out1) @ W2)                     (in-place over bufA rows)
//   h2  = gather(xw2) + self + b2                   (fp32, bufB packed N x 64)
//   logits[e] = dot(h2[ea], h2[eb])
// ---------------------------------------------------------------------------

typedef __attribute__((ext_vector_type(8))) short short8;
typedef __attribute__((ext_vector_type(4))) float f32x4;

__device__ __forceinline__ ushort f2bf(float v) {
    unsigned u = __float_as_uint(v);
    return (ushort)((u + 0x7FFFu + ((u >> 16) & 1u)) >> 16);
}
__device__ __forceinline__ float bf2f(ushort b) {
    return __uint_as_float(((unsigned)b) << 16);
}
__device__ __forceinline__ void split2(float v, ushort& h, ushort& l) {
    unsigned u = __float_as_uint(v);
    unsigned hb = (u + 0x7FFFu + ((u >> 16) & 1u)) & 0xFFFF0000u;
    h = (ushort)(hb >> 16);
    l = f2bf(v - __uint_as_float(hb));
}

// ---------------- CSR build ----------------
__global__ void zero_ints_kernel(int* __restrict__ p, int n) {
    int i = blockIdx.x * blockDim.x + threadIdx.x;
    if (i < n) p[i] = 0;
}
__global__ void hist_kernel(const int* __restrict__ tgt, int* __restrict__ counts, int e) {
    int i = blockIdx.x * blockDim.x + threadIdx.x;
    if (i < e) atomicAdd(&counts[tgt[i]], 1);
}
__global__ void dinv_kernel(const int* __restrict__ counts, float* __restrict__ dinv, int n) {
    int i = blockIdx.x * blockDim.x + threadIdx.x;
    if (i < n) dinv[i] = 1.0f / sqrtf((float)(counts[i] + 1));
}
__global__ __launch_bounds__(256)
void scan1_kernel(const int* __restrict__ counts, int* __restrict__ rowptr,
                  int* __restrict__ bsum, int n)
{
    __shared__ int sdata[256];
    const int t = threadIdx.x;
    const int base = blockIdx.x * 1024 + t * 4;
    int v[4];
#pragma unroll
    for (int i = 0; i < 4; i++) v[i] = (base + i < n) ? counts[base + i] : 0;
    int tsum = v[0] + v[1] + v[2] + v[3];
    sdata[t] = tsum;
    __syncthreads();
    for (int off = 1; off < 256; off <<= 1) {
        int x = (t >= off) ? sdata[t - off] : 0;
        __syncthreads();
        if (t >= off) sdata[t] += x;
        __syncthreads();
    }
    if (t == 255) bsum[blockIdx.x] = sdata[255];
    int run = sdata[t] - tsum;
#pragma unroll
    for (int i = 0; i < 4; i++) {
        if (base + i < n) rowptr[base + i] = run;
        run += v[i];
    }
}
__global__ __launch_bounds__(256)
void scan2_kernel(int* __restrict__ bsum, int nb)
{
    __shared__ int sdata[256];
    const int t = threadIdx.x;
    int v = (t < nb) ? bsum[t] : 0;
    sdata[t] = v;
    __syncthreads();
    for (int off = 1; off < 256; off <<= 1) {
        int x = (t >= off) ? sdata[t - off] : 0;
        __syncthreads();
        if (t >= off) sdata[t] += x;
        __syncthreads();
    }
    if (t < nb) bsum[t] = sdata[t] - v;
}
__global__ void scan3_kernel(int* __restrict__ rowptr, const int* __restrict__ bsum,
                             int n, int e_total)
{
    int i = blockIdx.x * blockDim.x + threadIdx.x;
    if (i < n) rowptr[i] += bsum[i >> 10];
    if (i == 0) rowptr[n] = e_total;
}
__global__ void scatter_kernel(const int* __restrict__ src, const int* __restrict__ tgt,
                               const float* __restrict__ dinv, const int* __restrict__ rowptr,
                               int* __restrict__ cursor, int2* __restrict__ ew, int e)
{
    int i = blockIdx.x * blockDim.x + threadIdx.x;
    if (i >= e) return;
    int s = src[i], t = tgt[i];
    int p = rowptr[t] + atomicAdd(&cursor[t], 1);
    ew[p] = make_int2(s, __float_as_int(dinv[s] * dinv[t]));
}

// ---------------- weight transpose + hi/lo split: W[K=128][N] -> T{h,l}[N][128]
__global__ void wsplit_kernel(const float* __restrict__ W, ushort* __restrict__ Th,
                              ushort* __restrict__ Tl, int N, int total)
{
    int o = blockIdx.x * blockDim.x + threadIdx.x;
    if (o >= total) return;
    int c = o >> 7;       // K = 128
    int k = o & 127;
    ushort h, l;
    split2(W[(size_t)k * N + c], h, l);
    Th[o] = h; Tl[o] = l;
}

// ---------------------------------------------------------------------------
// Split-bf16 MFMA GEMM. A: M x 128 fp32 row-major. BT{h,l}: BN x 128 bf16
// (pre-transposed weights). C = A @ W (+bias). Block: 128 rows, 4 waves,
// wave tile 32 x BN via mfma_f32_16x16x32_bf16.
//   C ~= Ah@Bh + Al@Bh + Ah@Bl   (err ~2^-15 relative)
// OUT_BF16: write bf16 into row slots of stride 256 ushorts (in-place over A's
// buffer is safe: each block's output rows are read only by itself, and all
// its global A-reads complete before the epilogue barriers).
// ---------------------------------------------------------------------------
template<int BN, bool RELU_IN, bool ADD_BIAS, bool OUT_BF16>
__global__ __launch_bounds__(256)
void gemm_mfma_kernel(const float* __restrict__ A,
                      const ushort* __restrict__ BTh, const ushort* __restrict__ BTl,
                      const float* __restrict__ bias,
                      float* Cf, ushort* Cb, int M)
{
    __shared__ ushort Ah[4][128][8];
    __shared__ ushort Al[4][128][8];
    __shared__ ushort Bh[4][BN][8];
    __shared__ ushort Bl[4][BN][8];

    const int tid = threadIdx.x;
    const int row0 = blockIdx.x * 128;
    const int wv = tid >> 6;
    const int l  = tid & 63;
    const int lr = l & 15;
    const int lk = l >> 4;

    constexpr int NT = BN / 16;
    f32x4 acc0[NT], acc1[NT];
#pragma unroll
    for (int n = 0; n < NT; ++n) {
        acc0[n] = (f32x4){0.f, 0.f, 0.f, 0.f};
        acc1[n] = (f32x4){0.f, 0.f, 0.f, 0.f};
    }

    for (int kk = 0; kk < 128; kk += 32) {
        // ---- stage A (fp32 -> hi/lo bf16), 128 rows x 32 k ----
        {
            const int r  = tid >> 1;
            const int kh = tid & 1;           // which 16-float half
            const int gr = row0 + r;
            float f[16];
            if (gr < M) {
                const float4* p = (const float4*)(A + (size_t)gr * 128 + kk + kh * 16);
                float4 q0 = p[0], q1 = p[1], q2 = p[2], q3 = p[3];
                f[0]=q0.x; f[1]=q0.y; f[2]=q0.z; f[3]=q0.w;
                f[4]=q1.x; f[5]=q1.y; f[6]=q1.z; f[7]=q1.w;
                f[8]=q2.x; f[9]=q2.y; f[10]=q2.z; f[11]=q2.w;
                f[12]=q3.x; f[13]=q3.y; f[14]=q3.z; f[15]=q3.w;
            } else {
#pragma unroll
                for (int j = 0; j < 16; j++) f[j] = 0.f;
            }
            if (RELU_IN) {
#pragma unroll
                for (int j = 0; j < 16; j++) f[j] = fmaxf(f[j], 0.f);
            }
#pragma unroll
            for (int uu = 0; uu < 2; ++uu) {
                short8 hv, lv;
#pragma unroll
                for (int j = 0; j < 8; ++j) {
                    ushort h, lo;
                    split2(f[8 * uu + j], h, lo);
                    hv[j] = (short)h; lv[j] = (short)lo;
                }
                *(short8*)&Ah[2 * kh + uu][r][0] = hv;
                *(short8*)&Al[2 * kh + uu][r][0] = lv;
            }
        }
        // ---- stage B (already bf16, just copy 32 k x BN) ----
        {
            constexpr int UPT = (4 * BN) / 256;   // units of 8 bf16
#pragma unroll
            for (int u = 0; u < UPT; ++u) {
                const int unit = tid * UPT + u;
                const int c   = unit >> 2;
                const int kgl = unit & 3;
                *(short8*)&Bh[kgl][c][0] = *(const short8*)(BTh + (size_t)c * 128 + kk + 8 * kgl);
                *(short8*)&Bl[kgl][c][0] = *(const short8*)(BTl + (size_t)c * 128 + kk + 8 * kgl);
            }
        }
        __syncthreads();

        // ---- MFMA: wave wv owns rows [32*wv, 32*wv+32) ----
        short8 ah0 = *(const short8*)&Ah[lk][wv * 32 + lr][0];
        short8 ah1 = *(const short8*)&Ah[lk][wv * 32 + 16 + lr][0];
        short8 al0 = *(const short8*)&Al[lk][wv * 32 + lr][0];
        short8 al1 = *(const short8*)&Al[lk][wv * 32 + 16 + lr][0];
#pragma unroll
        for (int n = 0; n < NT; ++n) {
            short8 bh = *(const short8*)&Bh[lk][n * 16 + lr][0];
            short8 bl = *(const short8*)&Bl[lk][n * 16 + lr][0];
            acc0[n] = __builtin_amdgcn_mfma_f32_16x16x32_bf16(ah0, bh, acc0[n], 0, 0, 0);
            acc1[n] = __builtin_amdgcn_mfma_f32_16x16x32_bf16(ah1, bh, acc1[n], 0, 0, 0);
            acc0[n] = __builtin_amdgcn_mfma_f32_16x16x32_bf16(al0, bh, acc0[n], 0, 0, 0);
            acc1[n] = __builtin_amdgcn_mfma_f32_16x16x32_bf16(al1, bh, acc1[n], 0, 0, 0);
            acc0[n] = __builtin_amdgcn_mfma_f32_16x16x32_bf16(ah0, bl, acc0[n], 0, 0, 0);
            acc1[n] = __builtin_amdgcn_mfma_f32_16x16x32_bf16(ah1, bl, acc1[n], 0, 0, 0);
        }
        __syncthreads();
    }

    // ---- epilogue. C frag: col = lane&15, row = 4*(lane>>4)+reg ----
    const int rbase = row0 + wv * 32 + lk * 4;
#pragma unroll
    for (int n = 0; n < NT; ++n) {
        const int gc = n * 16 + lr;
        const float bv = ADD_BIAS ? bias[gc] : 0.f;
#pragma unroll
        for (int reg = 0; reg < 4; ++reg) {
            const int gr0 = rbase + reg;
            if (gr0 < M) {
                const float v = acc0[n][reg] + bv;
                if (OUT_BF16) Cb[(size_t)gr0 * 256 + gc] = f2bf(v);
                else          Cf[(size_t)gr0 * 128 + gc] = v;
            }
            const int gr1 = rbase + 16 + reg;
            if (gr1 < M) {
                const float v = acc1[n][reg] + bv;
                if (OUT_BF16) Cb[(size_t)gr1 * 256 + gc] = f2bf(v);
                else          Cf[(size_t)gr1 * 128 + gc] = v;
            }
        }
    }
}

// ---------------------------------------------------------------------------
// CSR gather on bf16 rows (stride 256 ushorts), fp32 accumulate, + self + bias.
// One wave per node; 2-way edge unroll for load-level parallelism.
// ---------------------------------------------------------------------------
template<int D>
__global__ __launch_bounds__(256)
void gather_conv_bf_kernel(const ushort* __restrict__ xw, const float* __restrict__ dinv,
                           const int* __restrict__ rowptr, const int2* __restrict__ ew,
                           const float* __restrict__ bias, float* __restrict__ out, int n)
{
    const int node = blockIdx.x * 4 + (threadIdx.x >> 6);
    const int lane = threadIdx.x & 63;
    if (node >= n) return;
    const float dt = dinv[node];
    int j = rowptr[node];
    const int j1 = rowptr[node + 1];

    if (D == 128) {
        const unsigned self = *(const unsigned*)(xw + (size_t)node * 256 + 2 * lane);
        const float c = dt * dt;
        float accx = fmaf(__uint_as_float(self << 16), c, bias[2 * lane]);
        float accy = fmaf(__uint_as_float(self & 0xFFFF0000u), c, bias[2 * lane + 1]);
        for (; j + 1 < j1; j += 2) {
            const int2 p0 = ew[j];
            const int2 p1 = ew[j + 1];
            const unsigned v0 = *(const unsigned*)(xw + (size_t)p0.x * 256 + 2 * lane);
            const unsigned v1 = *(const unsigned*)(xw + (size_t)p1.x * 256 + 2 * lane);
            const float w0 = __int_as_float(p0.y), w1 = __int_as_float(p1.y);
            accx = fmaf(__uint_as_float(v0 << 16), w0, accx);
            accy = fmaf(__uint_as_float(v0 & 0xFFFF0000u), w0, accy);
            accx = fmaf(__uint_as_float(v1 << 16), w1, accx);
            accy = fmaf(__uint_as_float(v1 & 0xFFFF0000u), w1, accy);
        }
        if (j < j1) {
            const int2 p0 = ew[j];
            const unsigned v0 = *(const unsigned*)(xw + (size_t)p0.x * 256 + 2 * lane);
            const float w0 = __int_as_float(p0.y);
            accx = fmaf(__uint_as_float(v0 << 16), w0, accx);
            accy = fmaf(__uint_as_float(v0 & 0xFFFF0000u), w0, accy);
        }
        *(float2*)(out + (size_t)node * 128 + 2 * lane) = make_float2(accx, accy);
    } else {
        float acc = fmaf(bf2f(xw[(size_t)node * 256 + lane]), dt * dt, bias[lane]);
        for (; j + 1 < j1; j += 2) {
            const int2 p0 = ew[j];
            const int2 p1 = ew[j + 1];
            const float v0 = bf2f(xw[(size_t)p0.x * 256 + lane]);
            const float v1 = bf2f(xw[(size_t)p1.x * 256 + lane]);
            acc = fmaf(v0, __int_as_float(p0.y), acc);
            acc = fmaf(v1, __int_as_float(p1.y), acc);
        }
        if (j < j1) {
            const int2 p0 = ew[j];
            acc = fmaf(bf2f(xw[(size_t)p0.x * 256 + lane]), __int_as_float(p0.y), acc);
        }
        out[(size_t)node * 64 + lane] = acc;
    }
}

// ---------------------------------------------------------------------------
// logits[e] = dot(h[a], h[b]) over D=64 fp32. 16 lanes per edge.
// ---------------------------------------------------------------------------
__global__ void score_kernel(const float* __restrict__ h, const int* __restrict__ ea,
                             const int* __restrict__ eb, float* __restrict__ out, int E)
{
    long long gid = (long long)blockIdx.x * blockDim.x + threadIdx.x;
    int e = (int)(gid >> 4);
    int l = (int)(gid & 15);
    if (e >= E) return;
    int a = ea[e], b = eb[e];
    float4 va = *(const float4*)(h + (long long)a * 64 + l * 4);
    float4 vb = *(const float4*)(h + (long long)b * 64 + l * 4);
    float s = va.x * vb.x + va.y * vb.y + va.z * vb.z + va.w * vb.w;
    s += __shfl_xor(s, 8);
    s += __shfl_xor(s, 4);
    s += __shfl_xor(s, 2);
    s += __shfl_xor(s, 1);
    if (l == 0) out[e] = s;
}

extern "C" void kernel_launch(void* const* d_in, const int* in_sizes, int n_in,
                              void* d_out, int out_size, void* d_ws, size_t ws_size,
                              hipStream_t stream)
{
    const float* x              = (const float*)d_in[0];
    const int*   edge_index     = (const int*)d_in[1];
    const int*   pos_edge_index = (const int*)d_in[2];
    const float* W_init         = (const float*)d_in[3];
    const float* b_init         = (const float*)d_in[4];
    const float* W1             = (const float*)d_in[5];
    const float* b1             = (const float*)d_in[6];
    const float* W2             = (const float*)d_in[7];
    const float* b2             = (const float*)d_in[8];
    float* out = (float*)d_out;

    const int N     = in_sizes[0] / 128;   // 100000
    const int Epred = in_sizes[1] / 2;     // 200000
    const int E     = in_sizes[2] / 2;     // 500000

    const int* src = pos_edge_index;
    const int* tgt = pos_edge_index + E;
    const int* ea  = edge_index;
    const int* eb  = edge_index + Epred;

    // ---- workspace ----
    int2*  ew     = (int2*)d_ws;                    // E
    float* bufA   = (float*)(ew + E);               // N*128
    float* bufB   = bufA + (size_t)N * 128;         // N*128
    float* dinv   = bufB + (size_t)N * 128;         // N
    int*   counts = (int*)(dinv + N);               // N
    int*   cursor = counts + N;                     // N
    int*   rowptr = cursor + N;                     // N+2
    int*   bsum   = rowptr + N + 2;                 // 256
    ushort* wt    = (ushort*)(((uintptr_t)(bsum + 256) + 15) & ~(uintptr_t)15);
    ushort* WTih = wt;            // 128*128
    ushort* WTil = WTih + 16384;
    ushort* WT1h = WTil + 16384;
    ushort* WT1l = WT1h + 16384;
    ushort* WT2h = WT1l + 16384;  // 64*128
    ushort* WT2l = WT2h + 8192;

    const int BLK = 256;
    const int nb  = (N + 1023) / 1024;
    const int gemm_grid = (N + 127) / 128;

    // ---- CSR build ----
    zero_ints_kernel<<<(2 * N + BLK - 1) / BLK, BLK, 0, stream>>>(counts, 2 * N);
    hist_kernel<<<(E + BLK - 1) / BLK, BLK, 0, stream>>>(tgt, counts, E);
    dinv_kernel<<<(N + BLK - 1) / BLK, BLK, 0, stream>>>(counts, dinv, N);
    scan1_kernel<<<nb, 256, 0, stream>>>(counts, rowptr, bsum, N);
    scan2_kernel<<<1, 256, 0, stream>>>(bsum, nb);
    scan3_kernel<<<(N + BLK - 1) / BLK, BLK, 0, stream>>>(rowptr, bsum, N, E);
    scatter_kernel<<<(E + BLK - 1) / BLK, BLK, 0, stream>>>(src, tgt, dinv, rowptr, cursor, ew, E);

    // ---- weight transpose + split ----
    wsplit_kernel<<<64, BLK, 0, stream>>>(W_init, WTih, WTil, 128, 16384);
    wsplit_kernel<<<64, BLK, 0, stream>>>(W1,     WT1h, WT1l, 128, 16384);
    wsplit_kernel<<<32, BLK, 0, stream>>>(W2,     WT2h, WT2l,  64,  8192);

    // ---- h0 = x @ W_init + b_init  (fp32 -> bufB) ----
    gemm_mfma_kernel<128, false, true, false><<<gemm_grid, BLK, 0, stream>>>(
        x, WTih, WTil, b_init, bufB, nullptr, N);

    // ---- xw1 = bf16(h0 @ W1)  (in-place into bufB row slots) ----
    gemm_mfma_kernel<128, false, false, true><<<gemm_grid, BLK, 0, stream>>>(
        bufB, WT1h, WT1l, nullptr, nullptr, (ushort*)bufB, N);

    // ---- out1 = gather(xw1) + self + b1  (fp32 -> bufA) ----
    gather_conv_bf_kernel<128><<<(N + 3) / 4, BLK, 0, stream>>>(
        (const ushort*)bufB, dinv, rowptr, ew, b1, bufA, N);

    // ---- xw2 = bf16(relu(out1) @ W2)  (in-place into bufA row slots) ----
    gemm_mfma_kernel<64, true, false, true><<<gemm_grid, BLK, 0, stream>>>(
        bufA, WT2h, WT2l, nullptr, nullptr, (ushort*)bufA, N);

    // ---- h2 = gather(xw2) + self + b2  (fp32 packed N x 64 -> bufB) ----
    gather_conv_bf_kernel<64><<<(N + 3) / 4, BLK, 0, stream>>>(
        (const ushort*)bufA, dinv, rowptr, ew, b2, bufB, N);

    // ---- scoring ----
    score_kernel<<<((long long)Epred * 16 + BLK - 1) / BLK, BLK, 0, stream>>>(
        bufB, ea, eb, out, Epred);
}

// Round 4
// 241.522 us; speedup vs baseline: 2.1722x; 1.0285x over previous
//
#include <hip/hip_runtime.h>

// ---------------------------------------------------------------------------
// GCN link-prediction pipeline, R4.
//   gemm0: (h0h,h0l) = split_bf16(x @ W_init + b_init)        [2 bf16 planes]
//   gemm1: xw1 = bf16(h0 @ W1)                                 [bf16 plane]
//   gath1: (r1h,r1l) = split_bf16(relu(gather(xw1)+self+b1))   [2 bf16 planes]
//   gemm2: xw2 = bf16(r1 @ W2)                                 [bf16 plane]
//   gath2: h2 = bf16(gather(xw2)+self+b2)                      [bf16 plane]
//   score: logits[e] = dot(h2[ea], h2[eb])
// GEMMs: C ~= (Ah+Al) @ bf16(B)  (2 MFMAs/step, err ~2^-9 rel)
// ---------------------------------------------------------------------------

typedef __attribute__((ext_vector_type(8))) short short8;
typedef __attribute__((ext_vector_type(4))) float f32x4;

__device__ __forceinline__ ushort f2bf(float v) {
    unsigned u = __float_as_uint(v);
    return (ushort)((u + 0x7FFFu + ((u >> 16) & 1u)) >> 16);
}
__device__ __forceinline__ float bf2f(ushort b) {
    return __uint_as_float(((unsigned)b) << 16);
}
__device__ __forceinline__ void split2(float v, ushort& h, ushort& l) {
    unsigned u = __float_as_uint(v);
    unsigned hb = (u + 0x7FFFu + ((u >> 16) & 1u)) & 0xFFFF0000u;
    h = (ushort)(hb >> 16);
    l = f2bf(v - __uint_as_float(hb));
}

// ---------------- CSR build ----------------
__global__ void zero_ints_kernel(int* __restrict__ p, int n) {
    int i = blockIdx.x * blockDim.x + threadIdx.x;
    if (i < n) p[i] = 0;
}
__global__ void hist_kernel(const int* __restrict__ tgt, int* __restrict__ counts, int e) {
    int i = blockIdx.x * blockDim.x + threadIdx.x;
    if (i < e) atomicAdd(&counts[tgt[i]], 1);
}
__global__ void dinv_kernel(const int* __restrict__ counts, float* __restrict__ dinv, int n) {
    int i = blockIdx.x * blockDim.x + threadIdx.x;
    if (i < n) dinv[i] = 1.0f / sqrtf((float)(counts[i] + 1));
}
__global__ __launch_bounds__(256)
void scan1_kernel(const int* __restrict__ counts, int* __restrict__ rowptr,
                  int* __restrict__ bsum, int n)
{
    __shared__ int sdata[256];
    const int t = threadIdx.x;
    const int base = blockIdx.x * 1024 + t * 4;
    int v[4];
#pragma unroll
    for (int i = 0; i < 4; i++) v[i] = (base + i < n) ? counts[base + i] : 0;
    int tsum = v[0] + v[1] + v[2] + v[3];
    sdata[t] = tsum;
    __syncthreads();
    for (int off = 1; off < 256; off <<= 1) {
        int x = (t >= off) ? sdata[t - off] : 0;
        __syncthreads();
        if (t >= off) sdata[t] += x;
        __syncthreads();
    }
    if (t == 255) bsum[blockIdx.x] = sdata[255];
    int run = sdata[t] - tsum;
#pragma unroll
    for (int i = 0; i < 4; i++) {
        if (base + i < n) rowptr[base + i] = run;
        run += v[i];
    }
}
__global__ __launch_bounds__(256)
void scan2_kernel(int* __restrict__ bsum, int nb)
{
    __shared__ int sdata[256];
    const int t = threadIdx.x;
    int v = (t < nb) ? bsum[t] : 0;
    sdata[t] = v;
    __syncthreads();
    for (int off = 1; off < 256; off <<= 1) {
        int x = (t >= off) ? sdata[t - off] : 0;
        __syncthreads();
        if (t >= off) sdata[t] += x;
        __syncthreads();
    }
    if (t < nb) bsum[t] = sdata[t] - v;
}
__global__ void scan3_kernel(int* __restrict__ rowptr, const int* __restrict__ bsum,
                             int n, int e_total)
{
    int i = blockIdx.x * blockDim.x + threadIdx.x;
    if (i < n) rowptr[i] += bsum[i >> 10];
    if (i == 0) rowptr[n] = e_total;
}
__global__ void scatter_kernel(const int* __restrict__ src, const int* __restrict__ tgt,
                               const float* __restrict__ dinv, const int* __restrict__ rowptr,
                               int* __restrict__ cursor, int2* __restrict__ ew, int e)
{
    int i = blockIdx.x * blockDim.x + threadIdx.x;
    if (i >= e) return;
    int s = src[i], t = tgt[i];
    int p = rowptr[t] + atomicAdd(&cursor[t], 1);
    ew[p] = make_int2(s, __float_as_int(dinv[s] * dinv[t]));
}

// ---- weight transpose + bf16 round: W[K=128][N] -> T[N][128] bf16 ----
__global__ void wtrans_kernel(const float* __restrict__ W, ushort* __restrict__ T,
                              int N, int total)
{
    int o = blockIdx.x * blockDim.x + threadIdx.x;
    if (o >= total) return;
    int c = o >> 7;
    int k = o & 127;
    T[o] = f2bf(W[(size_t)k * N + c]);
}

// ---------------------------------------------------------------------------
// MFMA GEMM: C = A @ W (+bias), K=128. A either fp32 [M][128] (split in-kernel)
// or pre-split bf16 planes (Ahp, Alp) [M][128] each. B: BTh [BN][128] bf16.
// Block: 128 rows, 4 waves; wave = 32 rows x BN cols; mfma_f32_16x16x32_bf16.
// OUT_SPLIT: write hi/lo planes (Ch, Cl); else bf16 plane Ch, stride BN.
// ---------------------------------------------------------------------------
template<int BN, bool A_SPLIT, bool OUT_SPLIT, bool ADD_BIAS>
__global__ __launch_bounds__(256)
void gemm_mfma_kernel(const float* __restrict__ Af,
                      const ushort* __restrict__ Ahp, const ushort* __restrict__ Alp,
                      const ushort* __restrict__ BTh, const float* __restrict__ bias,
                      ushort* __restrict__ Ch, ushort* __restrict__ Cl, int M)
{
    __shared__ ushort Ah[4][128][8];
    __shared__ ushort Al[4][128][8];
    __shared__ ushort Bh[4][BN][8];

    const int tid = threadIdx.x;
    const int row0 = blockIdx.x * 128;
    const int wv = tid >> 6;
    const int l  = tid & 63;
    const int lr = l & 15;
    const int lk = l >> 4;

    constexpr int NT = BN / 16;
    f32x4 acc0[NT], acc1[NT];
#pragma unroll
    for (int n = 0; n < NT; ++n) {
        acc0[n] = (f32x4){0.f, 0.f, 0.f, 0.f};
        acc1[n] = (f32x4){0.f, 0.f, 0.f, 0.f};
    }

    for (int kk = 0; kk < 128; kk += 32) {
        // ---- stage A: 128 rows x 32 k into hi/lo planes ----
        {
            const int r  = tid >> 1;
            const int kh = tid & 1;            // which 16-k half
            const int gr = row0 + r;
            if (A_SPLIT) {
                short8 h0, h1, l0, l1;
                if (gr < M) {
                    const size_t o = (size_t)gr * 128 + kk + kh * 16;
                    h0 = *(const short8*)(Ahp + o);
                    h1 = *(const short8*)(Ahp + o + 8);
                    l0 = *(const short8*)(Alp + o);
                    l1 = *(const short8*)(Alp + o + 8);
                } else {
#pragma unroll
                    for (int j = 0; j < 8; j++) { h0[j] = 0; h1[j] = 0; l0[j] = 0; l1[j] = 0; }
                }
                *(short8*)&Ah[2 * kh + 0][r][0] = h0;
                *(short8*)&Ah[2 * kh + 1][r][0] = h1;
                *(short8*)&Al[2 * kh + 0][r][0] = l0;
                *(short8*)&Al[2 * kh + 1][r][0] = l1;
            } else {
                float f[16];
                if (gr < M) {
                    const float4* p = (const float4*)(Af + (size_t)gr * 128 + kk + kh * 16);
                    float4 q0 = p[0], q1 = p[1], q2 = p[2], q3 = p[3];
                    f[0]=q0.x; f[1]=q0.y; f[2]=q0.z; f[3]=q0.w;
                    f[4]=q1.x; f[5]=q1.y; f[6]=q1.z; f[7]=q1.w;
                    f[8]=q2.x; f[9]=q2.y; f[10]=q2.z; f[11]=q2.w;
                    f[12]=q3.x; f[13]=q3.y; f[14]=q3.z; f[15]=q3.w;
                } else {
#pragma unroll
                    for (int j = 0; j < 16; j++) f[j] = 0.f;
                }
#pragma unroll
                for (int uu = 0; uu < 2; ++uu) {
                    short8 hv, lv;
#pragma unroll
                    for (int j = 0; j < 8; ++j) {
                        ushort h, lo;
                        split2(f[8 * uu + j], h, lo);
                        hv[j] = (short)h; lv[j] = (short)lo;
                    }
                    *(short8*)&Ah[2 * kh + uu][r][0] = hv;
                    *(short8*)&Al[2 * kh + uu][r][0] = lv;
                }
            }
        }
        // ---- stage B: BN cols x 32 k ----
        {
            constexpr int UPT = (4 * BN) / 256;   // short8 units per thread
#pragma unroll
            for (int u = 0; u < UPT; ++u) {
                const int unit = tid * UPT + u;
                const int c   = unit >> 2;
                const int kgl = unit & 3;
                *(short8*)&Bh[kgl][c][0] = *(const short8*)(BTh + (size_t)c * 128 + kk + 8 * kgl);
            }
        }
        __syncthreads();

        short8 ah0 = *(const short8*)&Ah[lk][wv * 32 + lr][0];
        short8 ah1 = *(const short8*)&Ah[lk][wv * 32 + 16 + lr][0];
        short8 al0 = *(const short8*)&Al[lk][wv * 32 + lr][0];
        short8 al1 = *(const short8*)&Al[lk][wv * 32 + 16 + lr][0];
#pragma unroll
        for (int n = 0; n < NT; ++n) {
            short8 bh = *(const short8*)&Bh[lk][n * 16 + lr][0];
            acc0[n] = __builtin_amdgcn_mfma_f32_16x16x32_bf16(ah0, bh, acc0[n], 0, 0, 0);
            acc1[n] = __builtin_amdgcn_mfma_f32_16x16x32_bf16(ah1, bh, acc1[n], 0, 0, 0);
            acc0[n] = __builtin_amdgcn_mfma_f32_16x16x32_bf16(al0, bh, acc0[n], 0, 0, 0);
            acc1[n] = __builtin_amdgcn_mfma_f32_16x16x32_bf16(al1, bh, acc1[n], 0, 0, 0);
        }
        __syncthreads();
    }

    // ---- epilogue. C frag: col = lane&15, row = 4*(lane>>4)+reg ----
    const int rbase = row0 + wv * 32 + lk * 4;
#pragma unroll
    for (int n = 0; n < NT; ++n) {
        const int gc = n * 16 + lr;
        const float bv = ADD_BIAS ? bias[gc] : 0.f;
#pragma unroll
        for (int reg = 0; reg < 4; ++reg) {
#pragma unroll
            for (int half = 0; half < 2; ++half) {
                const int gr = rbase + 16 * half + reg;
                if (gr < M) {
                    const float v = (half ? acc1[n][reg] : acc0[n][reg]) + bv;
                    if (OUT_SPLIT) {
                        ushort h, lo;
                        split2(v, h, lo);
                        Ch[(size_t)gr * 128 + gc] = h;
                        Cl[(size_t)gr * 128 + gc] = lo;
                    } else {
                        Ch[(size_t)gr * BN + gc] = f2bf(v);
                    }
                }
            }
        }
    }
}

// ---------------------------------------------------------------------------
// gather1: out = relu(sum_j xw[col_j]*w_j + xw[t]*dinv^2 + b1), split-bf16 out.
// xw: bf16 plane [N][128]. One wave/node, 4-way edge unroll.
// ---------------------------------------------------------------------------
__global__ __launch_bounds__(256)
void gather1_kernel(const ushort* __restrict__ xw, const float* __restrict__ dinv,
                    const int* __restrict__ rowptr, const int2* __restrict__ ew,
                    const float* __restrict__ bias,
                    ushort* __restrict__ outh, ushort* __restrict__ outl, int n)
{
    const int node = blockIdx.x * 4 + (threadIdx.x >> 6);
    const int lane = threadIdx.x & 63;
    if (node >= n) return;
    const float dt = dinv[node];
    int j = rowptr[node];
    const int j1 = rowptr[node + 1];

    const unsigned self = *(const unsigned*)(xw + (size_t)node * 128 + 2 * lane);
    const float c = dt * dt;
    float accx = fmaf(__uint_as_float(self << 16), c, bias[2 * lane]);
    float accy = fmaf(__uint_as_float(self & 0xFFFF0000u), c, bias[2 * lane + 1]);

    for (; j + 3 < j1; j += 4) {
        const int2 p0 = ew[j], p1 = ew[j + 1], p2 = ew[j + 2], p3 = ew[j + 3];
        const unsigned v0 = *(const unsigned*)(xw + (size_t)p0.x * 128 + 2 * lane);
        const unsigned v1 = *(const unsigned*)(xw + (size_t)p1.x * 128 + 2 * lane);
        const unsigned v2 = *(const unsigned*)(xw + (size_t)p2.x * 128 + 2 * lane);
        const unsigned v3 = *(const unsigned*)(xw + (size_t)p3.x * 128 + 2 * lane);
        const float w0 = __int_as_float(p0.y), w1 = __int_as_float(p1.y);
        const float w2 = __int_as_float(p2.y), w3 = __int_as_float(p3.y);
        accx = fmaf(__uint_as_float(v0 << 16), w0, accx);
        accy = fmaf(__uint_as_float(v0 & 0xFFFF0000u), w0, accy);
        accx = fmaf(__uint_as_float(v1 << 16), w1, accx);
        accy = fmaf(__uint_as_float(v1 & 0xFFFF0000u), w1, accy);
        accx = fmaf(__uint_as_float(v2 << 16), w2, accx);
        accy = fmaf(__uint_as_float(v2 & 0xFFFF0000u), w2, accy);
        accx = fmaf(__uint_as_float(v3 << 16), w3, accx);
        accy = fmaf(__uint_as_float(v3 & 0xFFFF0000u), w3, accy);
    }
    for (; j < j1; ++j) {
        const int2 p0 = ew[j];
        const unsigned v0 = *(const unsigned*)(xw + (size_t)p0.x * 128 + 2 * lane);
        const float w0 = __int_as_float(p0.y);
        accx = fmaf(__uint_as_float(v0 << 16), w0, accx);
        accy = fmaf(__uint_as_float(v0 & 0xFFFF0000u), w0, accy);
    }

    const float rx = fmaxf(accx, 0.f);
    const float ry = fmaxf(accy, 0.f);
    ushort hx, lx, hy, ly;
    split2(rx, hx, lx);
    split2(ry, hy, ly);
    *(unsigned*)(outh + (size_t)node * 128 + 2 * lane) = (unsigned)hx | ((unsigned)hy << 16);
    *(unsigned*)(outl + (size_t)node * 128 + 2 * lane) = (unsigned)lx | ((unsigned)ly << 16);
}

// ---------------------------------------------------------------------------
// gather2: h2 = bf16(sum_j xw[col_j]*w_j + xw[t]*dinv^2 + b2).
// xw: bf16 plane [N][64]. One wave/node (lane = dim), 4-way edge unroll.
// ---------------------------------------------------------------------------
__global__ __launch_bounds__(256)
void gather2_kernel(const ushort* __restrict__ xw, const float* __restrict__ dinv,
                    const int* __restrict__ rowptr, const int2* __restrict__ ew,
                    const float* __restrict__ bias, ushort* __restrict__ out, int n)
{
    const int node = blockIdx.x * 4 + (threadIdx.x >> 6);
    const int lane = threadIdx.x & 63;
    if (node >= n) return;
    const float dt = dinv[node];
    int j = rowptr[node];
    const int j1 = rowptr[node + 1];

    float acc = fmaf(bf2f(xw[(size_t)node * 64 + lane]), dt * dt, bias[lane]);
    for (; j + 3 < j1; j += 4) {
        const int2 p0 = ew[j], p1 = ew[j + 1], p2 = ew[j + 2], p3 = ew[j + 3];
        const float v0 = bf2f(xw[(size_t)p0.x * 64 + lane]);
        const float v1 = bf2f(xw[(size_t)p1.x * 64 + lane]);
        const float v2 = bf2f(xw[(size_t)p2.x * 64 + lane]);
        const float v3 = bf2f(xw[(size_t)p3.x * 64 + lane]);
        acc = fmaf(v0, __int_as_float(p0.y), acc);
        acc = fmaf(v1, __int_as_float(p1.y), acc);
        acc = fmaf(v2, __int_as_float(p2.y), acc);
        acc = fmaf(v3, __int_as_float(p3.y), acc);
    }
    for (; j < j1; ++j) {
        const int2 p0 = ew[j];
        acc = fmaf(bf2f(xw[(size_t)p0.x * 64 + lane]), __int_as_float(p0.y), acc);
    }
    out[(size_t)node * 64 + lane] = f2bf(acc);
}

// ---------------------------------------------------------------------------
// logits[e] = dot(h2[a], h2[b]) over D=64 bf16. 16 lanes/edge, uint2 loads.
// ---------------------------------------------------------------------------
__global__ void score_kernel(const ushort* __restrict__ h, const int* __restrict__ ea,
                             const int* __restrict__ eb, float* __restrict__ out, int E)
{
    long long gid = (long long)blockIdx.x * blockDim.x + threadIdx.x;
    int e = (int)(gid >> 4);
    int l = (int)(gid & 15);
    if (e >= E) return;
    int a = ea[e], b = eb[e];
    uint2 ua = *(const uint2*)(h + (size_t)a * 64 + 4 * l);
    uint2 ub = *(const uint2*)(h + (size_t)b * 64 + 4 * l);
    float s;
    s  = __uint_as_float(ua.x << 16)          * __uint_as_float(ub.x << 16);
    s += __uint_as_float(ua.x & 0xFFFF0000u)  * __uint_as_float(ub.x & 0xFFFF0000u);
    s += __uint_as_float(ua.y << 16)          * __uint_as_float(ub.y << 16);
    s += __uint_as_float(ua.y & 0xFFFF0000u)  * __uint_as_float(ub.y & 0xFFFF0000u);
    s += __shfl_xor(s, 8);
    s += __shfl_xor(s, 4);
    s += __shfl_xor(s, 2);
    s += __shfl_xor(s, 1);
    if (l == 0) out[e] = s;
}

extern "C" void kernel_launch(void* const* d_in, const int* in_sizes, int n_in,
                              void* d_out, int out_size, void* d_ws, size_t ws_size,
                              hipStream_t stream)
{
    const float* x              = (const float*)d_in[0];
    const int*   edge_index     = (const int*)d_in[1];
    const int*   pos_edge_index = (const int*)d_in[2];
    const float* W_init         = (const float*)d_in[3];
    const float* b_init         = (const float*)d_in[4];
    const float* W1             = (const float*)d_in[5];
    const float* b1             = (const float*)d_in[6];
    const float* W2             = (const float*)d_in[7];
    const float* b2             = (const float*)d_in[8];
    float* out = (float*)d_out;

    const int N     = in_sizes[0] / 128;   // 100000
    const int Epred = in_sizes[1] / 2;     // 200000
    const int E     = in_sizes[2] / 2;     // 500000

    const int* src = pos_edge_index;
    const int* tgt = pos_edge_index + E;
    const int* ea  = edge_index;
    const int* eb  = edge_index + Epred;

    // ---- workspace ----
    int2*   ew   = (int2*)d_ws;                      // E
    ushort* regA = (ushort*)(ew + E);                // N*128   (xw1 / xw2)
    ushort* regB = regA + (size_t)N * 128;           // 2*N*128 (h0 pair / r1 pair / h2)
    float*  dinv = (float*)(regB + (size_t)2 * N * 128);
    int*   counts = (int*)(dinv + N);                // N
    int*   cursor = counts + N;                      // N
    int*   rowptr = cursor + N;                      // N+2
    int*   bsum   = rowptr + N + 2;                  // 256
    ushort* WTi = (ushort*)(((uintptr_t)(bsum + 256) + 15) & ~(uintptr_t)15);  // 128*128
    ushort* WT1 = WTi + 16384;                       // 128*128
    ushort* WT2 = WT1 + 16384;                       // 64*128

    ushort* h0h = regB;
    ushort* h0l = regB + (size_t)N * 128;
    ushort* xw1 = regA;
    ushort* r1h = regB;                // overwrites h0 (dead after gemm1)
    ushort* r1l = regB + (size_t)N * 128;
    ushort* xw2 = regA;                // overwrites xw1 (dead after gather1)
    ushort* h2  = regB;                // overwrites r1 (dead after gemm2)

    const int BLK = 256;
    const int nb  = (N + 1023) / 1024;
    const int gemm_grid = (N + 127) / 128;

    // ---- CSR build ----
    zero_ints_kernel<<<(2 * N + BLK - 1) / BLK, BLK, 0, stream>>>(counts, 2 * N);
    hist_kernel<<<(E + BLK - 1) / BLK, BLK, 0, stream>>>(tgt, counts, E);
    dinv_kernel<<<(N + BLK - 1) / BLK, BLK, 0, stream>>>(counts, dinv, N);
    scan1_kernel<<<nb, 256, 0, stream>>>(counts, rowptr, bsum, N);
    scan2_kernel<<<1, 256, 0, stream>>>(bsum, nb);
    scan3_kernel<<<(N + BLK - 1) / BLK, BLK, 0, stream>>>(rowptr, bsum, N, E);
    scatter_kernel<<<(E + BLK - 1) / BLK, BLK, 0, stream>>>(src, tgt, dinv, rowptr, cursor, ew, E);

    // ---- weight transpose (bf16 hi only) ----
    wtrans_kernel<<<64, BLK, 0, stream>>>(W_init, WTi, 128, 16384);
    wtrans_kernel<<<64, BLK, 0, stream>>>(W1,     WT1, 128, 16384);
    wtrans_kernel<<<32, BLK, 0, stream>>>(W2,     WT2,  64,  8192);

    // ---- gemm0: (h0h,h0l) = split(x @ W_init + b_init) ----
    gemm_mfma_kernel<128, false, true, true><<<gemm_grid, BLK, 0, stream>>>(
        x, nullptr, nullptr, WTi, b_init, h0h, h0l, N);

    // ---- gemm1: xw1 = bf16(h0 @ W1) ----
    gemm_mfma_kernel<128, true, false, false><<<gemm_grid, BLK, 0, stream>>>(
        nullptr, h0h, h0l, WT1, nullptr, xw1, nullptr, N);

    // ---- gather1: (r1h,r1l) = split(relu(agg(xw1)+self+b1)) ----
    gather1_kernel<<<(N + 3) / 4, BLK, 0, stream>>>(xw1, dinv, rowptr, ew, b1, r1h, r1l, N);

    // ---- gemm2: xw2 = bf16(r1 @ W2) ----
    gemm_mfma_kernel<64, true, false, false><<<gemm_grid, BLK, 0, stream>>>(
        nullptr, r1h, r1l, WT2, nullptr, xw2, nullptr, N);

    // ---- gather2: h2 = bf16(agg(xw2)+self+b2) ----
    gather2_kernel<<<(N + 3) / 4, BLK, 0, stream>>>(xw2, dinv, rowptr, ew, b2, h2, N);

    // ---- scoring ----
    score_kernel<<<((long long)Epred * 16 + BLK - 1) / BLK, BLK, 0, stream>>>(
        h2, ea, eb, out, Epred);
}

// Round 5
// 209.762 us; speedup vs baseline: 2.5010x; 1.1514x over previous
//
#include <hip/hip_runtime.h>

// ---------------------------------------------------------------------------
// GCN link-prediction pipeline, R5.
//   fused01: xw1 = bf16( (x @ W_init + b_init) @ W1 )   [h0 split-bf16 in LDS]
//   gath1:   (r1h,r1l) = split_bf16(relu(gather(xw1)+self+b1))
//   gemm2:   xw2 = bf16(r1 @ W2)
//   gath2:   h2 = bf16(gather(xw2)+self+b2)
//   score:   logits[e] = dot(h2[ea], h2[eb])
// MFMA GEMMs use OPERAND-SWAPPED mfma (bfrag, afrag) -> transposed C layout:
//   lane holds 4 consecutive output cols of one row -> 8B packed bf16 stores.
// ---------------------------------------------------------------------------

typedef __attribute__((ext_vector_type(8))) short short8;
typedef __attribute__((ext_vector_type(4))) float f32x4;

__device__ __forceinline__ ushort f2bf(float v) {
    unsigned u = __float_as_uint(v);
    return (ushort)((u + 0x7FFFu + ((u >> 16) & 1u)) >> 16);
}
__device__ __forceinline__ float bf2f(ushort b) {
    return __uint_as_float(((unsigned)b) << 16);
}
__device__ __forceinline__ void split2(float v, ushort& h, ushort& l) {
    unsigned u = __float_as_uint(v);
    unsigned hb = (u + 0x7FFFu + ((u >> 16) & 1u)) & 0xFFFF0000u;
    h = (ushort)(hb >> 16);
    l = f2bf(v - __uint_as_float(hb));
}

// ---------------- CSR build ----------------
__global__ void zero_ints_kernel(int* __restrict__ p, int n) {
    int i = blockIdx.x * blockDim.x + threadIdx.x;
    if (i < n) p[i] = 0;
}
__global__ void hist_kernel(const int* __restrict__ tgt, int* __restrict__ counts, int e) {
    int i = blockIdx.x * blockDim.x + threadIdx.x;
    if (i < e) atomicAdd(&counts[tgt[i]], 1);
}
__global__ void dinv_kernel(const int* __restrict__ counts, float* __restrict__ dinv, int n) {
    int i = blockIdx.x * blockDim.x + threadIdx.x;
    if (i < n) dinv[i] = 1.0f / sqrtf((float)(counts[i] + 1));
}
__global__ __launch_bounds__(256)
void scan1_kernel(const int* __restrict__ counts, int* __restrict__ rowptr,
                  int* __restrict__ bsum, int n)
{
    __shared__ int sdata[256];
    const int t = threadIdx.x;
    const int base = blockIdx.x * 1024 + t * 4;
    int v[4];
#pragma unroll
    for (int i = 0; i < 4; i++) v[i] = (base + i < n) ? counts[base + i] : 0;
    int tsum = v[0] + v[1] + v[2] + v[3];
    sdata[t] = tsum;
    __syncthreads();
    for (int off = 1; off < 256; off <<= 1) {
        int x = (t >= off) ? sdata[t - off] : 0;
        __syncthreads();
        if (t >= off) sdata[t] += x;
        __syncthreads();
    }
    if (t == 255) bsum[blockIdx.x] = sdata[255];
    int run = sdata[t] - tsum;
#pragma unroll
    for (int i = 0; i < 4; i++) {
        if (base + i < n) rowptr[base + i] = run;
        run += v[i];
    }
}
__global__ __launch_bounds__(256)
void scan2_kernel(int* __restrict__ bsum, int nb)
{
    __shared__ int sdata[256];
    const int t = threadIdx.x;
    int v = (t < nb) ? bsum[t] : 0;
    sdata[t] = v;
    __syncthreads();
    for (int off = 1; off < 256; off <<= 1) {
        int x = (t >= off) ? sdata[t - off] : 0;
        __syncthreads();
        if (t >= off) sdata[t] += x;
        __syncthreads();
    }
    if (t < nb) bsum[t] = sdata[t] - v;
}
__global__ void scan3_kernel(int* __restrict__ rowptr, const int* __restrict__ bsum,
                             int n, int e_total)
{
    int i = blockIdx.x * blockDim.x + threadIdx.x;
    if (i < n) rowptr[i] += bsum[i >> 10];
    if (i == 0) rowptr[n] = e_total;
}
__global__ void scatter_kernel(const int* __restrict__ src, const int* __restrict__ tgt,
                               const float* __restrict__ dinv, const int* __restrict__ rowptr,
                               int* __restrict__ cursor, int2* __restrict__ ew, int e)
{
    int i = blockIdx.x * blockDim.x + threadIdx.x;
    if (i >= e) return;
    int s = src[i], t = tgt[i];
    int p = rowptr[t] + atomicAdd(&cursor[t], 1);
    ew[p] = make_int2(s, __float_as_int(dinv[s] * dinv[t]));
}

// ---- weight transpose + bf16 round: W[K=128][N] -> T[N][128] bf16 ----
__global__ void wtrans_kernel(const float* __restrict__ W, ushort* __restrict__ T,
                              int N, int total)
{
    int o = blockIdx.x * blockDim.x + threadIdx.x;
    if (o >= total) return;
    int c = o >> 7;
    int k = o & 127;
    T[o] = f2bf(W[(size_t)k * N + c]);
}

// ---------------------------------------------------------------------------
// Fused gemm0+gemm1: xw1 = bf16((x @ Wi + bi) @ W1).
// Block: 128 rows, 4 waves. h0 kept as split-bf16 planes in LDS
// ([16 kslots][128 rows][8]). Swapped-operand MFMA -> coalesced 8B stores.
// ---------------------------------------------------------------------------
__global__ __launch_bounds__(256)
void fused_gemm01_kernel(const float* __restrict__ x,
                         const ushort* __restrict__ WTi, const ushort* __restrict__ WT1,
                         const float* __restrict__ bias, ushort* __restrict__ xw1, int M)
{
    __shared__ ushort raw[36864];                       // 72 KiB
    ushort (*H0h)[128][8] = (ushort(*)[128][8])raw;           // 16 ks, 32 KiB
    ushort (*H0l)[128][8] = (ushort(*)[128][8])(raw + 16384); // 16 ks, 32 KiB
    ushort (*Bs)[128][8]  = (ushort(*)[128][8])(raw + 32768); // 4 ks,   8 KiB

    const int tid = threadIdx.x;
    const int row0 = blockIdx.x * 128;
    const int wv = tid >> 6;
    const int l  = tid & 63;
    const int lr = l & 15;
    const int lk = l >> 4;

    f32x4 acc0[8], acc1[8];
#pragma unroll
    for (int n = 0; n < 8; ++n) {
        acc0[n] = (f32x4){0.f, 0.f, 0.f, 0.f};
        acc1[n] = (f32x4){0.f, 0.f, 0.f, 0.f};
    }

    // ================= phase 1: acc = (x @ Wi)^T-layout =================
    for (int kk = 0; kk < 128; kk += 32) {
        {   // stage A chunk (fp32 -> split) into H0h/H0l kslots 0..3
            const int r  = tid >> 1;
            const int kh = tid & 1;
            const int gr = row0 + r;
            float f[16];
            if (gr < M) {
                const float4* p = (const float4*)(x + (size_t)gr * 128 + kk + kh * 16);
                float4 q0 = p[0], q1 = p[1], q2 = p[2], q3 = p[3];
                f[0]=q0.x; f[1]=q0.y; f[2]=q0.z; f[3]=q0.w;
                f[4]=q1.x; f[5]=q1.y; f[6]=q1.z; f[7]=q1.w;
                f[8]=q2.x; f[9]=q2.y; f[10]=q2.z; f[11]=q2.w;
                f[12]=q3.x; f[13]=q3.y; f[14]=q3.z; f[15]=q3.w;
            } else {
#pragma unroll
                for (int j = 0; j < 16; j++) f[j] = 0.f;
            }
#pragma unroll
            for (int uu = 0; uu < 2; ++uu) {
                short8 hv, lv;
#pragma unroll
                for (int j = 0; j < 8; ++j) {
                    ushort h, lo;
                    split2(f[8 * uu + j], h, lo);
                    hv[j] = (short)h; lv[j] = (short)lo;
                }
                *(short8*)&H0h[2 * kh + uu][r][0] = hv;
                *(short8*)&H0l[2 * kh + uu][r][0] = lv;
            }
        }
        {   // stage B chunk (Wi^T)
#pragma unroll
            for (int u = 0; u < 2; ++u) {
                const int unit = tid * 2 + u;
                const int c   = unit >> 2;
                const int kgl = unit & 3;
                *(short8*)&Bs[kgl][c][0] = *(const short8*)(WTi + (size_t)c * 128 + kk + 8 * kgl);
            }
        }
        __syncthreads();
        short8 ah0 = *(const short8*)&H0h[lk][wv * 32 + lr][0];
        short8 ah1 = *(const short8*)&H0h[lk][wv * 32 + 16 + lr][0];
        short8 al0 = *(const short8*)&H0l[lk][wv * 32 + lr][0];
        short8 al1 = *(const short8*)&H0l[lk][wv * 32 + 16 + lr][0];
#pragma unroll
        for (int n = 0; n < 8; ++n) {
            short8 bh = *(const short8*)&Bs[lk][n * 16 + lr][0];
            acc0[n] = __builtin_amdgcn_mfma_f32_16x16x32_bf16(bh, ah0, acc0[n], 0, 0, 0);
            acc1[n] = __builtin_amdgcn_mfma_f32_16x16x32_bf16(bh, ah1, acc1[n], 0, 0, 0);
            acc0[n] = __builtin_amdgcn_mfma_f32_16x16x32_bf16(bh, al0, acc0[n], 0, 0, 0);
            acc1[n] = __builtin_amdgcn_mfma_f32_16x16x32_bf16(bh, al1, acc1[n], 0, 0, 0);
        }
        __syncthreads();
    }

    // ===== phase 2: h0 = acc + bias -> split planes in LDS =====
    // acc layout (swapped): row m = wv*32 + 16*half + lr ; col c = n*16 + 4*lk + reg
#pragma unroll
    for (int n = 0; n < 8; ++n) {
        const float4 b4 = *(const float4*)(bias + n * 16 + 4 * lk);
        const float bb[4] = {b4.x, b4.y, b4.z, b4.w};
        const int ks = 2 * n + (lk >> 1);
        const int jo = (lk & 1) * 4;
#pragma unroll
        for (int half = 0; half < 2; ++half) {
            const int m = wv * 32 + 16 * half + lr;
            uint2 uh, ul;
            unsigned hw[4], lw[4];
#pragma unroll
            for (int r = 0; r < 4; ++r) {
                ushort h, lo;
                split2((half ? acc1[n][r] : acc0[n][r]) + bb[r], h, lo);
                hw[r] = h; lw[r] = lo;
            }
            uh.x = hw[0] | (hw[1] << 16); uh.y = hw[2] | (hw[3] << 16);
            ul.x = lw[0] | (lw[1] << 16); ul.y = lw[2] | (lw[3] << 16);
            *(uint2*)&H0h[ks][m][jo] = uh;
            *(uint2*)&H0l[ks][m][jo] = ul;
        }
    }
    __syncthreads();

    // ================= phase 3: acc = (h0 @ W1)^T-layout =================
#pragma unroll
    for (int n = 0; n < 8; ++n) {
        acc0[n] = (f32x4){0.f, 0.f, 0.f, 0.f};
        acc1[n] = (f32x4){0.f, 0.f, 0.f, 0.f};
    }
    for (int kk = 0; kk < 4; ++kk) {
        {
#pragma unroll
            for (int u = 0; u < 2; ++u) {
                const int unit = tid * 2 + u;
                const int c   = unit >> 2;
                const int kgl = unit & 3;
                *(short8*)&Bs[kgl][c][0] = *(const short8*)(WT1 + (size_t)c * 128 + kk * 32 + 8 * kgl);
            }
        }
        __syncthreads();
        short8 ah0 = *(const short8*)&H0h[kk * 4 + lk][wv * 32 + lr][0];
        short8 ah1 = *(const short8*)&H0h[kk * 4 + lk][wv * 32 + 16 + lr][0];
        short8 al0 = *(const short8*)&H0l[kk * 4 + lk][wv * 32 + lr][0];
        short8 al1 = *(const short8*)&H0l[kk * 4 + lk][wv * 32 + 16 + lr][0];
#pragma unroll
        for (int n = 0; n < 8; ++n) {
            short8 bh = *(const short8*)&Bs[lk][n * 16 + lr][0];
            acc0[n] = __builtin_amdgcn_mfma_f32_16x16x32_bf16(bh, ah0, acc0[n], 0, 0, 0);
            acc1[n] = __builtin_amdgcn_mfma_f32_16x16x32_bf16(bh, ah1, acc1[n], 0, 0, 0);
            acc0[n] = __builtin_amdgcn_mfma_f32_16x16x32_bf16(bh, al0, acc0[n], 0, 0, 0);
            acc1[n] = __builtin_amdgcn_mfma_f32_16x16x32_bf16(bh, al1, acc1[n], 0, 0, 0);
        }
        __syncthreads();
    }

    // ===== phase 4: xw1 = bf16(acc), packed 8B coalesced stores =====
#pragma unroll
    for (int n = 0; n < 8; ++n) {
#pragma unroll
        for (int half = 0; half < 2; ++half) {
            const int m = row0 + wv * 32 + 16 * half + lr;
            if (m < M) {
                uint2 u;
                const f32x4 a = half ? acc1[n] : acc0[n];
                u.x = (unsigned)f2bf(a[0]) | ((unsigned)f2bf(a[1]) << 16);
                u.y = (unsigned)f2bf(a[2]) | ((unsigned)f2bf(a[3]) << 16);
                *(uint2*)(xw1 + (size_t)m * 128 + n * 16 + 4 * lk) = u;
            }
        }
    }
}

// ---------------------------------------------------------------------------
// gemm2: xw2 = bf16(r1 @ W2). A = split planes r1h/r1l [M][128].
// BN=64, NT=4. Swapped-operand MFMA, packed 8B stores.
// ---------------------------------------------------------------------------
__global__ __launch_bounds__(256)
void gemm2_kernel(const ushort* __restrict__ Ahp, const ushort* __restrict__ Alp,
                  const ushort* __restrict__ WT2, ushort* __restrict__ xw2, int M)
{
    __shared__ ushort Ah[4][128][8];
    __shared__ ushort Al[4][128][8];
    __shared__ ushort Bs[4][64][8];

    const int tid = threadIdx.x;
    const int row0 = blockIdx.x * 128;
    const int wv = tid >> 6;
    const int l  = tid & 63;
    const int lr = l & 15;
    const int lk = l >> 4;

    f32x4 acc0[4], acc1[4];
#pragma unroll
    for (int n = 0; n < 4; ++n) {
        acc0[n] = (f32x4){0.f, 0.f, 0.f, 0.f};
        acc1[n] = (f32x4){0.f, 0.f, 0.f, 0.f};
    }

    for (int kk = 0; kk < 128; kk += 32) {
        {
            const int r  = tid >> 1;
            const int kh = tid & 1;
            const int gr = row0 + r;
            short8 h0, h1, l0, l1;
            if (gr < M) {
                const size_t o = (size_t)gr * 128 + kk + kh * 16;
                h0 = *(const short8*)(Ahp + o);
                h1 = *(const short8*)(Ahp + o + 8);
                l0 = *(const short8*)(Alp + o);
                l1 = *(const short8*)(Alp + o + 8);
            } else {
#pragma unroll
                for (int j = 0; j < 8; j++) { h0[j] = 0; h1[j] = 0; l0[j] = 0; l1[j] = 0; }
            }
            *(short8*)&Ah[2 * kh + 0][r][0] = h0;
            *(short8*)&Ah[2 * kh + 1][r][0] = h1;
            *(short8*)&Al[2 * kh + 0][r][0] = l0;
            *(short8*)&Al[2 * kh + 1][r][0] = l1;
        }
        {
            const int c   = tid >> 2;
            const int kgl = tid & 3;
            *(short8*)&Bs[kgl][c][0] = *(const short8*)(WT2 + (size_t)c * 128 + kk + 8 * kgl);
        }
        __syncthreads();
        short8 ah0 = *(const short8*)&Ah[lk][wv * 32 + lr][0];
        short8 ah1 = *(const short8*)&Ah[lk][wv * 32 + 16 + lr][0];
        short8 al0 = *(const short8*)&Al[lk][wv * 32 + lr][0];
        short8 al1 = *(const short8*)&Al[lk][wv * 32 + 16 + lr][0];
#pragma unroll
        for (int n = 0; n < 4; ++n) {
            short8 bh = *(const short8*)&Bs[lk][n * 16 + lr][0];
            acc0[n] = __builtin_amdgcn_mfma_f32_16x16x32_bf16(bh, ah0, acc0[n], 0, 0, 0);
            acc1[n] = __builtin_amdgcn_mfma_f32_16x16x32_bf16(bh, ah1, acc1[n], 0, 0, 0);
            acc0[n] = __builtin_amdgcn_mfma_f32_16x16x32_bf16(bh, al0, acc0[n], 0, 0, 0);
            acc1[n] = __builtin_amdgcn_mfma_f32_16x16x32_bf16(bh, al1, acc1[n], 0, 0, 0);
        }
        __syncthreads();
    }

#pragma unroll
    for (int n = 0; n < 4; ++n) {
#pragma unroll
        for (int half = 0; half < 2; ++half) {
            const int m = row0 + wv * 32 + 16 * half + lr;
            if (m < M) {
                uint2 u;
                const f32x4 a = half ? acc1[n] : acc0[n];
                u.x = (unsigned)f2bf(a[0]) | ((unsigned)f2bf(a[1]) << 16);
                u.y = (unsigned)f2bf(a[2]) | ((unsigned)f2bf(a[3]) << 16);
                *(uint2*)(xw2 + (size_t)m * 64 + n * 16 + 4 * lk) = u;
            }
        }
    }
}

// ---------------------------------------------------------------------------
// gather1: (r1h,r1l) = split(relu(agg(xw1)+self+b1)). One wave/node, 4-way unroll.
// ---------------------------------------------------------------------------
__global__ __launch_bounds__(256)
void gather1_kernel(const ushort* __restrict__ xw, const float* __restrict__ dinv,
                    const int* __restrict__ rowptr, const int2* __restrict__ ew,
                    const float* __restrict__ bias,
                    ushort* __restrict__ outh, ushort* __restrict__ outl, int n)
{
    const int node = blockIdx.x * 4 + (threadIdx.x >> 6);
    const int lane = threadIdx.x & 63;
    if (node >= n) return;
    const float dt = dinv[node];
    int j = rowptr[node];
    const int j1 = rowptr[node + 1];

    const unsigned self = *(const unsigned*)(xw + (size_t)node * 128 + 2 * lane);
    const float c = dt * dt;
    float accx = fmaf(__uint_as_float(self << 16), c, bias[2 * lane]);
    float accy = fmaf(__uint_as_float(self & 0xFFFF0000u), c, bias[2 * lane + 1]);

    for (; j + 3 < j1; j += 4) {
        const int2 p0 = ew[j], p1 = ew[j + 1], p2 = ew[j + 2], p3 = ew[j + 3];
        const unsigned v0 = *(const unsigned*)(xw + (size_t)p0.x * 128 + 2 * lane);
        const unsigned v1 = *(const unsigned*)(xw + (size_t)p1.x * 128 + 2 * lane);
        const unsigned v2 = *(const unsigned*)(xw + (size_t)p2.x * 128 + 2 * lane);
        const unsigned v3 = *(const unsigned*)(xw + (size_t)p3.x * 128 + 2 * lane);
        const float w0 = __int_as_float(p0.y), w1 = __int_as_float(p1.y);
        const float w2 = __int_as_float(p2.y), w3 = __int_as_float(p3.y);
        accx = fmaf(__uint_as_float(v0 << 16), w0, accx);
        accy = fmaf(__uint_as_float(v0 & 0xFFFF0000u), w0, accy);
        accx = fmaf(__uint_as_float(v1 << 16), w1, accx);
        accy = fmaf(__uint_as_float(v1 & 0xFFFF0000u), w1, accy);
        accx = fmaf(__uint_as_float(v2 << 16), w2, accx);
        accy = fmaf(__uint_as_float(v2 & 0xFFFF0000u), w2, accy);
        accx = fmaf(__uint_as_float(v3 << 16), w3, accx);
        accy = fmaf(__uint_as_float(v3 & 0xFFFF0000u), w3, accy);
    }
    for (; j < j1; ++j) {
        const int2 p0 = ew[j];
        const unsigned v0 = *(const unsigned*)(xw + (size_t)p0.x * 128 + 2 * lane);
        const float w0 = __int_as_float(p0.y);
        accx = fmaf(__uint_as_float(v0 << 16), w0, accx);
        accy = fmaf(__uint_as_float(v0 & 0xFFFF0000u), w0, accy);
    }

    const float rx = fmaxf(accx, 0.f);
    const float ry = fmaxf(accy, 0.f);
    ushort hx, lx, hy, ly;
    split2(rx, hx, lx);
    split2(ry, hy, ly);
    *(unsigned*)(outh + (size_t)node * 128 + 2 * lane) = (unsigned)hx | ((unsigned)hy << 16);
    *(unsigned*)(outl + (size_t)node * 128 + 2 * lane) = (unsigned)lx | ((unsigned)ly << 16);
}

// ---------------------------------------------------------------------------
// gather2: h2 = bf16(agg(xw2)+self+b2). xw: [N][64] bf16.
// ---------------------------------------------------------------------------
__global__ __launch_bounds__(256)
void gather2_kernel(const ushort* __restrict__ xw, const float* __restrict__ dinv,
                    const int* __restrict__ rowptr, const int2* __restrict__ ew,
                    const float* __restrict__ bias, ushort* __restrict__ out, int n)
{
    const int node = blockIdx.x * 4 + (threadIdx.x >> 6);
    const int lane = threadIdx.x & 63;
    if (node >= n) return;
    const float dt = dinv[node];
    int j = rowptr[node];
    const int j1 = rowptr[node + 1];

    float acc = fmaf(bf2f(xw[(size_t)node * 64 + lane]), dt * dt, bias[lane]);
    for (; j + 3 < j1; j += 4) {
        const int2 p0 = ew[j], p1 = ew[j + 1], p2 = ew[j + 2], p3 = ew[j + 3];
        const float v0 = bf2f(xw[(size_t)p0.x * 64 + lane]);
        const float v1 = bf2f(xw[(size_t)p1.x * 64 + lane]);
        const float v2 = bf2f(xw[(size_t)p2.x * 64 + lane]);
        const float v3 = bf2f(xw[(size_t)p3.x * 64 + lane]);
        acc = fmaf(v0, __int_as_float(p0.y), acc);
        acc = fmaf(v1, __int_as_float(p1.y), acc);
        acc = fmaf(v2, __int_as_float(p2.y), acc);
        acc = fmaf(v3, __int_as_float(p3.y), acc);
    }
    for (; j < j1; ++j) {
        const int2 p0 = ew[j];
        acc = fmaf(bf2f(xw[(size_t)p0.x * 64 + lane]), __int_as_float(p0.y), acc);
    }
    out[(size_t)node * 64 + lane] = f2bf(acc);
}

// ---------------------------------------------------------------------------
// logits[e] = dot(h2[a], h2[b]) over D=64 bf16. 16 lanes/edge, uint2 loads.
// ---------------------------------------------------------------------------
__global__ void score_kernel(const ushort* __restrict__ h, const int* __restrict__ ea,
                             const int* __restrict__ eb, float* __restrict__ out, int E)
{
    long long gid = (long long)blockIdx.x * blockDim.x + threadIdx.x;
    int e = (int)(gid >> 4);
    int l = (int)(gid & 15);
    if (e >= E) return;
    int a = ea[e], b = eb[e];
    uint2 ua = *(const uint2*)(h + (size_t)a * 64 + 4 * l);
    uint2 ub = *(const uint2*)(h + (size_t)b * 64 + 4 * l);
    float s;
    s  = __uint_as_float(ua.x << 16)          * __uint_as_float(ub.x << 16);
    s += __uint_as_float(ua.x & 0xFFFF0000u)  * __uint_as_float(ub.x & 0xFFFF0000u);
    s += __uint_as_float(ua.y << 16)          * __uint_as_float(ub.y << 16);
    s += __uint_as_float(ua.y & 0xFFFF0000u)  * __uint_as_float(ub.y & 0xFFFF0000u);
    s += __shfl_xor(s, 8);
    s += __shfl_xor(s, 4);
    s += __shfl_xor(s, 2);
    s += __shfl_xor(s, 1);
    if (l == 0) out[e] = s;
}

extern "C" void kernel_launch(void* const* d_in, const int* in_sizes, int n_in,
                              void* d_out, int out_size, void* d_ws, size_t ws_size,
                              hipStream_t stream)
{
    const float* x              = (const float*)d_in[0];
    const int*   edge_index     = (const int*)d_in[1];
    const int*   pos_edge_index = (const int*)d_in[2];
    const float* W_init         = (const float*)d_in[3];
    const float* b_init         = (const float*)d_in[4];
    const float* W1             = (const float*)d_in[5];
    const float* b1             = (const float*)d_in[6];
    const float* W2             = (const float*)d_in[7];
    const float* b2             = (const float*)d_in[8];
    float* out = (float*)d_out;

    const int N     = in_sizes[0] / 128;   // 100000
    const int Epred = in_sizes[1] / 2;     // 200000
    const int E     = in_sizes[2] / 2;     // 500000

    const int* src = pos_edge_index;
    const int* tgt = pos_edge_index + E;
    const int* ea  = edge_index;
    const int* eb  = edge_index + Epred;

    // ---- workspace ----
    int2*   ew   = (int2*)d_ws;                      // E
    ushort* regA = (ushort*)(ew + E);                // N*128   (xw1 / xw2)
    ushort* regB = regA + (size_t)N * 128;           // 2*N*128 (r1 pair / h2)
    float*  dinv = (float*)(regB + (size_t)2 * N * 128);
    int*   counts = (int*)(dinv + N);                // N
    int*   cursor = counts + N;                      // N
    int*   rowptr = cursor + N;                      // N+2
    int*   bsum   = rowptr + N + 2;                  // 256
    ushort* WTi = (ushort*)(((uintptr_t)(bsum + 256) + 15) & ~(uintptr_t)15);  // 128*128
    ushort* WT1 = WTi + 16384;                       // 128*128
    ushort* WT2 = WT1 + 16384;                       // 64*128

    ushort* xw1 = regA;
    ushort* r1h = regB;
    ushort* r1l = regB + (size_t)N * 128;
    ushort* xw2 = regA;                // overwrites xw1 (dead after gather1)
    ushort* h2  = regB;                // overwrites r1 (dead after gemm2)

    const int BLK = 256;
    const int nb  = (N + 1023) / 1024;
    const int gemm_grid = (N + 127) / 128;

    // ---- CSR build ----
    zero_ints_kernel<<<(2 * N + BLK - 1) / BLK, BLK, 0, stream>>>(counts, 2 * N);
    hist_kernel<<<(E + BLK - 1) / BLK, BLK, 0, stream>>>(tgt, counts, E);
    dinv_kernel<<<(N + BLK - 1) / BLK, BLK, 0, stream>>>(counts, dinv, N);
    scan1_kernel<<<nb, 256, 0, stream>>>(counts, rowptr, bsum, N);
    scan2_kernel<<<1, 256, 0, stream>>>(bsum, nb);
    scan3_kernel<<<(N + BLK - 1) / BLK, BLK, 0, stream>>>(rowptr, bsum, N, E);
    scatter_kernel<<<(E + BLK - 1) / BLK, BLK, 0, stream>>>(src, tgt, dinv, rowptr, cursor, ew, E);

    // ---- weight transpose ----
    wtrans_kernel<<<64, BLK, 0, stream>>>(W_init, WTi, 128, 16384);
    wtrans_kernel<<<64, BLK, 0, stream>>>(W1,     WT1, 128, 16384);
    wtrans_kernel<<<32, BLK, 0, stream>>>(W2,     WT2,  64,  8192);

    // ---- fused gemm0+gemm1: xw1 = bf16((x@Wi+bi)@W1) ----
    fused_gemm01_kernel<<<gemm_grid, BLK, 0, stream>>>(x, WTi, WT1, b_init, xw1, N);

    // ---- gather1: (r1h,r1l) = split(relu(agg(xw1)+self+b1)) ----
    gather1_kernel<<<(N + 3) / 4, BLK, 0, stream>>>(xw1, dinv, rowptr, ew, b1, r1h, r1l, N);

    // ---- gemm2: xw2 = bf16(r1 @ W2) ----
    gemm2_kernel<<<gemm_grid, BLK, 0, stream>>>(r1h, r1l, WT2, xw2, N);

    // ---- gather2: h2 = bf16(agg(xw2)+self+b2) ----
    gather2_kernel<<<(N + 3) / 4, BLK, 0, stream>>>(xw2, dinv, rowptr, ew, b2, h2, N);

    // ---- scoring ----
    score_kernel<<<((long long)Epred * 16 + BLK - 1) / BLK, BLK, 0, stream>>>(
        h2, ea, eb, out, Epred);
}

// Round 6
// 196.924 us; speedup vs baseline: 2.6641x; 1.0652x over previous
//
#include <hip/hip_runtime.h>

// ---------------------------------------------------------------------------
// GCN link-prediction pipeline, R6.
//   fused01: xw1 = bf16( (x @ W_init + b_init) @ W1 )   [h0 split-bf16 in LDS]
//   gath1:   r1 = bf16(relu(gather(xw1)+self+b1))       [single bf16 plane]
//   gemm2:   xw2 = bf16(r1 @ W2)                        [single-plane A, 2 MFMA]
//   gath2:   h2 = bf16(gather(xw2)+self+b2)
//   score:   logits[e] = dot(h2[ea], h2[eb])            [8 lanes/edge, uint4]
// MFMA GEMMs use OPERAND-SWAPPED mfma (bfrag, afrag) -> transposed C layout:
//   lane holds 4 consecutive output cols of one row -> 8B packed bf16 stores.
// ---------------------------------------------------------------------------

typedef __attribute__((ext_vector_type(8))) short short8;
typedef __attribute__((ext_vector_type(4))) float f32x4;

__device__ __forceinline__ ushort f2bf(float v) {
    unsigned u = __float_as_uint(v);
    return (ushort)((u + 0x7FFFu + ((u >> 16) & 1u)) >> 16);
}
__device__ __forceinline__ float bf2f(ushort b) {
    return __uint_as_float(((unsigned)b) << 16);
}
__device__ __forceinline__ void split2(float v, ushort& h, ushort& l) {
    unsigned u = __float_as_uint(v);
    unsigned hb = (u + 0x7FFFu + ((u >> 16) & 1u)) & 0xFFFF0000u;
    h = (ushort)(hb >> 16);
    l = f2bf(v - __uint_as_float(hb));
}

// ---------------- CSR build ----------------
__global__ void zero_ints_kernel(int* __restrict__ p, int n) {
    int i = blockIdx.x * blockDim.x + threadIdx.x;
    if (i < n) p[i] = 0;
}
__global__ void hist_kernel(const int* __restrict__ tgt, int* __restrict__ counts, int e) {
    int i = blockIdx.x * blockDim.x + threadIdx.x;
    if (i < e) atomicAdd(&counts[tgt[i]], 1);
}
// scan1: per-1024-block exclusive scan of counts -> rowptr (+ block sums),
// fused with dinv computation.
__global__ __launch_bounds__(256)
void scan1_kernel(const int* __restrict__ counts, int* __restrict__ rowptr,
                  int* __restrict__ bsum, float* __restrict__ dinv, int n)
{
    __shared__ int sdata[256];
    const int t = threadIdx.x;
    const int base = blockIdx.x * 1024 + t * 4;
    int v[4];
#pragma unroll
    for (int i = 0; i < 4; i++) v[i] = (base + i < n) ? counts[base + i] : 0;
#pragma unroll
    for (int i = 0; i < 4; i++)
        if (base + i < n) dinv[base + i] = 1.0f / sqrtf((float)(v[i] + 1));
    int tsum = v[0] + v[1] + v[2] + v[3];
    sdata[t] = tsum;
    __syncthreads();
    for (int off = 1; off < 256; off <<= 1) {
        int x = (t >= off) ? sdata[t - off] : 0;
        __syncthreads();
        if (t >= off) sdata[t] += x;
        __syncthreads();
    }
    if (t == 255) bsum[blockIdx.x] = sdata[255];
    int run = sdata[t] - tsum;
#pragma unroll
    for (int i = 0; i < 4; i++) {
        if (base + i < n) rowptr[base + i] = run;
        run += v[i];
    }
}
__global__ __launch_bounds__(256)
void scan2_kernel(int* __restrict__ bsum, int nb)
{
    __shared__ int sdata[256];
    const int t = threadIdx.x;
    int v = (t < nb) ? bsum[t] : 0;
    sdata[t] = v;
    __syncthreads();
    for (int off = 1; off < 256; off <<= 1) {
        int x = (t >= off) ? sdata[t - off] : 0;
        __syncthreads();
        if (t >= off) sdata[t] += x;
        __syncthreads();
    }
    if (t < nb) bsum[t] = sdata[t] - v;
}
__global__ void scan3_kernel(int* __restrict__ rowptr, const int* __restrict__ bsum,
                             int n, int e_total)
{
    int i = blockIdx.x * blockDim.x + threadIdx.x;
    if (i < n) rowptr[i] += bsum[i >> 10];
    if (i == 0) rowptr[n] = e_total;
}
__global__ void scatter_kernel(const int* __restrict__ src, const int* __restrict__ tgt,
                               const float* __restrict__ dinv, const int* __restrict__ rowptr,
                               int* __restrict__ cursor, int2* __restrict__ ew, int e)
{
    int i = blockIdx.x * blockDim.x + threadIdx.x;
    if (i >= e) return;
    int s = src[i], t = tgt[i];
    int p = rowptr[t] + atomicAdd(&cursor[t], 1);
    ew[p] = make_int2(s, __float_as_int(dinv[s] * dinv[t]));
}

// ---- all weight transposes in one kernel: W[K=128][N] -> T[N][128] bf16 ----
__global__ void wtrans_all_kernel(const float* __restrict__ Wi, const float* __restrict__ W1,
                                  const float* __restrict__ W2,
                                  ushort* __restrict__ Ti, ushort* __restrict__ T1,
                                  ushort* __restrict__ T2)
{
    int o = blockIdx.x * blockDim.x + threadIdx.x;
    if (o < 16384) {
        int c = o >> 7, k = o & 127;
        Ti[o] = f2bf(Wi[(size_t)k * 128 + c]);
    } else if (o < 32768) {
        int p = o - 16384;
        int c = p >> 7, k = p & 127;
        T1[p] = f2bf(W1[(size_t)k * 128 + c]);
    } else if (o < 40960) {
        int p = o - 32768;
        int c = p >> 7, k = p & 127;
        T2[p] = f2bf(W2[(size_t)k * 64 + c]);
    }
}

// ---------------------------------------------------------------------------
// Fused gemm0+gemm1: xw1 = bf16((x @ Wi + bi) @ W1).
// Block: 128 rows, 4 waves. h0 kept as split-bf16 planes in LDS.
// ---------------------------------------------------------------------------
__global__ __launch_bounds__(256)
void fused_gemm01_kernel(const float* __restrict__ x,
                         const ushort* __restrict__ WTi, const ushort* __restrict__ WT1,
                         const float* __restrict__ bias, ushort* __restrict__ xw1, int M)
{
    __shared__ ushort raw[36864];                       // 72 KiB
    ushort (*H0h)[128][8] = (ushort(*)[128][8])raw;           // 16 ks, 32 KiB
    ushort (*H0l)[128][8] = (ushort(*)[128][8])(raw + 16384); // 16 ks, 32 KiB
    ushort (*Bs)[128][8]  = (ushort(*)[128][8])(raw + 32768); // 4 ks,   8 KiB

    const int tid = threadIdx.x;
    const int row0 = blockIdx.x * 128;
    const int wv = tid >> 6;
    const int l  = tid & 63;
    const int lr = l & 15;
    const int lk = l >> 4;

    f32x4 acc0[8], acc1[8];
#pragma unroll
    for (int n = 0; n < 8; ++n) {
        acc0[n] = (f32x4){0.f, 0.f, 0.f, 0.f};
        acc1[n] = (f32x4){0.f, 0.f, 0.f, 0.f};
    }

    // ================= phase 1: acc = (x @ Wi)^T-layout =================
    for (int kk = 0; kk < 128; kk += 32) {
        {   // stage A chunk (fp32 -> split) into H0h/H0l kslots 0..3
            const int r  = tid >> 1;
            const int kh = tid & 1;
            const int gr = row0 + r;
            float f[16];
            if (gr < M) {
                const float4* p = (const float4*)(x + (size_t)gr * 128 + kk + kh * 16);
                float4 q0 = p[0], q1 = p[1], q2 = p[2], q3 = p[3];
                f[0]=q0.x; f[1]=q0.y; f[2]=q0.z; f[3]=q0.w;
                f[4]=q1.x; f[5]=q1.y; f[6]=q1.z; f[7]=q1.w;
                f[8]=q2.x; f[9]=q2.y; f[10]=q2.z; f[11]=q2.w;
                f[12]=q3.x; f[13]=q3.y; f[14]=q3.z; f[15]=q3.w;
            } else {
#pragma unroll
                for (int j = 0; j < 16; j++) f[j] = 0.f;
            }
#pragma unroll
            for (int uu = 0; uu < 2; ++uu) {
                short8 hv, lv;
#pragma unroll
                for (int j = 0; j < 8; ++j) {
                    ushort h, lo;
                    split2(f[8 * uu + j], h, lo);
                    hv[j] = (short)h; lv[j] = (short)lo;
                }
                *(short8*)&H0h[2 * kh + uu][r][0] = hv;
                *(short8*)&H0l[2 * kh + uu][r][0] = lv;
            }
        }
        {   // stage B chunk (Wi^T)
#pragma unroll
            for (int u = 0; u < 2; ++u) {
                const int unit = tid * 2 + u;
                const int c   = unit >> 2;
                const int kgl = unit & 3;
                *(short8*)&Bs[kgl][c][0] = *(const short8*)(WTi + (size_t)c * 128 + kk + 8 * kgl);
            }
        }
        __syncthreads();
        short8 ah0 = *(const short8*)&H0h[lk][wv * 32 + lr][0];
        short8 ah1 = *(const short8*)&H0h[lk][wv * 32 + 16 + lr][0];
        short8 al0 = *(const short8*)&H0l[lk][wv * 32 + lr][0];
        short8 al1 = *(const short8*)&H0l[lk][wv * 32 + 16 + lr][0];
#pragma unroll
        for (int n = 0; n < 8; ++n) {
            short8 bh = *(const short8*)&Bs[lk][n * 16 + lr][0];
            acc0[n] = __builtin_amdgcn_mfma_f32_16x16x32_bf16(bh, ah0, acc0[n], 0, 0, 0);
            acc1[n] = __builtin_amdgcn_mfma_f32_16x16x32_bf16(bh, ah1, acc1[n], 0, 0, 0);
            acc0[n] = __builtin_amdgcn_mfma_f32_16x16x32_bf16(bh, al0, acc0[n], 0, 0, 0);
            acc1[n] = __builtin_amdgcn_mfma_f32_16x16x32_bf16(bh, al1, acc1[n], 0, 0, 0);
        }
        __syncthreads();
    }

    // ===== phase 2: h0 = acc + bias -> split planes in LDS =====
    // acc layout (swapped): row m = wv*32 + 16*half + lr ; col c = n*16 + 4*lk + reg
#pragma unroll
    for (int n = 0; n < 8; ++n) {
        const float4 b4 = *(const float4*)(bias + n * 16 + 4 * lk);
        const float bb[4] = {b4.x, b4.y, b4.z, b4.w};
        const int ks = 2 * n + (lk >> 1);
        const int jo = (lk & 1) * 4;
#pragma unroll
        for (int half = 0; half < 2; ++half) {
            const int m = wv * 32 + 16 * half + lr;
            uint2 uh, ul;
            unsigned hw[4], lw[4];
#pragma unroll
            for (int r = 0; r < 4; ++r) {
                ushort h, lo;
                split2((half ? acc1[n][r] : acc0[n][r]) + bb[r], h, lo);
                hw[r] = h; lw[r] = lo;
            }
            uh.x = hw[0] | (hw[1] << 16); uh.y = hw[2] | (hw[3] << 16);
            ul.x = lw[0] | (lw[1] << 16); ul.y = lw[2] | (lw[3] << 16);
            *(uint2*)&H0h[ks][m][jo] = uh;
            *(uint2*)&H0l[ks][m][jo] = ul;
        }
    }
    __syncthreads();

    // ================= phase 3: acc = (h0 @ W1)^T-layout =================
#pragma unroll
    for (int n = 0; n < 8; ++n) {
        acc0[n] = (f32x4){0.f, 0.f, 0.f, 0.f};
        acc1[n] = (f32x4){0.f, 0.f, 0.f, 0.f};
    }
    for (int kk = 0; kk < 4; ++kk) {
        {
#pragma unroll
            for (int u = 0; u < 2; ++u) {
                const int unit = tid * 2 + u;
                const int c   = unit >> 2;
                const int kgl = unit & 3;
                *(short8*)&Bs[kgl][c][0] = *(const short8*)(WT1 + (size_t)c * 128 + kk * 32 + 8 * kgl);
            }
        }
        __syncthreads();
        short8 ah0 = *(const short8*)&H0h[kk * 4 + lk][wv * 32 + lr][0];
        short8 ah1 = *(const short8*)&H0h[kk * 4 + lk][wv * 32 + 16 + lr][0];
        short8 al0 = *(const short8*)&H0l[kk * 4 + lk][wv * 32 + lr][0];
        short8 al1 = *(const short8*)&H0l[kk * 4 + lk][wv * 32 + 16 + lr][0];
#pragma unroll
        for (int n = 0; n < 8; ++n) {
            short8 bh = *(const short8*)&Bs[lk][n * 16 + lr][0];
            acc0[n] = __builtin_amdgcn_mfma_f32_16x16x32_bf16(bh, ah0, acc0[n], 0, 0, 0);
            acc1[n] = __builtin_amdgcn_mfma_f32_16x16x32_bf16(bh, ah1, acc1[n], 0, 0, 0);
            acc0[n] = __builtin_amdgcn_mfma_f32_16x16x32_bf16(bh, al0, acc0[n], 0, 0, 0);
            acc1[n] = __builtin_amdgcn_mfma_f32_16x16x32_bf16(bh, al1, acc1[n], 0, 0, 0);
        }
        __syncthreads();
    }

    // ===== phase 4: xw1 = bf16(acc), packed 8B coalesced stores =====
#pragma unroll
    for (int n = 0; n < 8; ++n) {
#pragma unroll
        for (int half = 0; half < 2; ++half) {
            const int m = row0 + wv * 32 + 16 * half + lr;
            if (m < M) {
                uint2 u;
                const f32x4 a = half ? acc1[n] : acc0[n];
                u.x = (unsigned)f2bf(a[0]) | ((unsigned)f2bf(a[1]) << 16);
                u.y = (unsigned)f2bf(a[2]) | ((unsigned)f2bf(a[3]) << 16);
                *(uint2*)(xw1 + (size_t)m * 128 + n * 16 + 4 * lk) = u;
            }
        }
    }
}

// ---------------------------------------------------------------------------
// gemm2: xw2 = bf16(r1 @ W2). A = single bf16 plane r1 [M][128].
// BN=64, NT=4. Swapped-operand MFMA, packed 8B stores.
// ---------------------------------------------------------------------------
__global__ __launch_bounds__(256)
void gemm2_kernel(const ushort* __restrict__ Ap, const ushort* __restrict__ WT2,
                  ushort* __restrict__ xw2, int M)
{
    __shared__ ushort Ah[4][128][8];
    __shared__ ushort Bs[4][64][8];

    const int tid = threadIdx.x;
    const int row0 = blockIdx.x * 128;
    const int wv = tid >> 6;
    const int l  = tid & 63;
    const int lr = l & 15;
    const int lk = l >> 4;

    f32x4 acc0[4], acc1[4];
#pragma unroll
    for (int n = 0; n < 4; ++n) {
        acc0[n] = (f32x4){0.f, 0.f, 0.f, 0.f};
        acc1[n] = (f32x4){0.f, 0.f, 0.f, 0.f};
    }

    for (int kk = 0; kk < 128; kk += 32) {
        {
            const int r  = tid >> 1;
            const int kh = tid & 1;
            const int gr = row0 + r;
            short8 h0, h1;
            if (gr < M) {
                const size_t o = (size_t)gr * 128 + kk + kh * 16;
                h0 = *(const short8*)(Ap + o);
                h1 = *(const short8*)(Ap + o + 8);
            } else {
#pragma unroll
                for (int j = 0; j < 8; j++) { h0[j] = 0; h1[j] = 0; }
            }
            *(short8*)&Ah[2 * kh + 0][r][0] = h0;
            *(short8*)&Ah[2 * kh + 1][r][0] = h1;
        }
        {
            const int c   = tid >> 2;
            const int kgl = tid & 3;
            *(short8*)&Bs[kgl][c][0] = *(const short8*)(WT2 + (size_t)c * 128 + kk + 8 * kgl);
        }
        __syncthreads();
        short8 ah0 = *(const short8*)&Ah[lk][wv * 32 + lr][0];
        short8 ah1 = *(const short8*)&Ah[lk][wv * 32 + 16 + lr][0];
#pragma unroll
        for (int n = 0; n < 4; ++n) {
            short8 bh = *(const short8*)&Bs[lk][n * 16 + lr][0];
            acc0[n] = __builtin_amdgcn_mfma_f32_16x16x32_bf16(bh, ah0, acc0[n], 0, 0, 0);
            acc1[n] = __builtin_amdgcn_mfma_f32_16x16x32_bf16(bh, ah1, acc1[n], 0, 0, 0);
        }
        __syncthreads();
    }

#pragma unroll
    for (int n = 0; n < 4; ++n) {
#pragma unroll
        for (int half = 0; half < 2; ++half) {
            const int m = row0 + wv * 32 + 16 * half + lr;
            if (m < M) {
                uint2 u;
                const f32x4 a = half ? acc1[n] : acc0[n];
                u.x = (unsigned)f2bf(a[0]) | ((unsigned)f2bf(a[1]) << 16);
                u.y = (unsigned)f2bf(a[2]) | ((unsigned)f2bf(a[3]) << 16);
                *(uint2*)(xw2 + (size_t)m * 64 + n * 16 + 4 * lk) = u;
            }
        }
    }
}

// ---------------------------------------------------------------------------
// gather1: r1 = bf16(relu(agg(xw1)+self+b1)). One wave/node, 4-way unroll.
// ---------------------------------------------------------------------------
__global__ __launch_bounds__(256)
void gather1_kernel(const ushort* __restrict__ xw, const float* __restrict__ dinv,
                    const int* __restrict__ rowptr, const int2* __restrict__ ew,
                    const float* __restrict__ bias, ushort* __restrict__ outp, int n)
{
    const int node = blockIdx.x * 4 + (threadIdx.x >> 6);
    const int lane = threadIdx.x & 63;
    if (node >= n) return;
    const float dt = dinv[node];
    int j = rowptr[node];
    const int j1 = rowptr[node + 1];

    const unsigned self = *(const unsigned*)(xw + (size_t)node * 128 + 2 * lane);
    const float c = dt * dt;
    float accx = fmaf(__uint_as_float(self << 16), c, bias[2 * lane]);
    float accy = fmaf(__uint_as_float(self & 0xFFFF0000u), c, bias[2 * lane + 1]);

    for (; j + 3 < j1; j += 4) {
        const int2 p0 = ew[j], p1 = ew[j + 1], p2 = ew[j + 2], p3 = ew[j + 3];
        const unsigned v0 = *(const unsigned*)(xw + (size_t)p0.x * 128 + 2 * lane);
        const unsigned v1 = *(const unsigned*)(xw + (size_t)p1.x * 128 + 2 * lane);
        const unsigned v2 = *(const unsigned*)(xw + (size_t)p2.x * 128 + 2 * lane);
        const unsigned v3 = *(const unsigned*)(xw + (size_t)p3.x * 128 + 2 * lane);
        const float w0 = __int_as_float(p0.y), w1 = __int_as_float(p1.y);
        const float w2 = __int_as_float(p2.y), w3 = __int_as_float(p3.y);
        accx = fmaf(__uint_as_float(v0 << 16), w0, accx);
        accy = fmaf(__uint_as_float(v0 & 0xFFFF0000u), w0, accy);
        accx = fmaf(__uint_as_float(v1 << 16), w1, accx);
        accy = fmaf(__uint_as_float(v1 & 0xFFFF0000u), w1, accy);
        accx = fmaf(__uint_as_float(v2 << 16), w2, accx);
        accy = fmaf(__uint_as_float(v2 & 0xFFFF0000u), w2, accy);
        accx = fmaf(__uint_as_float(v3 << 16), w3, accx);
        accy = fmaf(__uint_as_float(v3 & 0xFFFF0000u), w3, accy);
    }
    for (; j < j1; ++j) {
        const int2 p0 = ew[j];
        const unsigned v0 = *(const unsigned*)(xw + (size_t)p0.x * 128 + 2 * lane);
        const float w0 = __int_as_float(p0.y);
        accx = fmaf(__uint_as_float(v0 << 16), w0, accx);
        accy = fmaf(__uint_as_float(v0 & 0xFFFF0000u), w0, accy);
    }

    const float rx = fmaxf(accx, 0.f);
    const float ry = fmaxf(accy, 0.f);
    *(unsigned*)(outp + (size_t)node * 128 + 2 * lane) =
        (unsigned)f2bf(rx) | ((unsigned)f2bf(ry) << 16);
}

// ---------------------------------------------------------------------------
// gather2: h2 = bf16(agg(xw2)+self+b2). xw: [N][64] bf16.
// ---------------------------------------------------------------------------
__global__ __launch_bounds__(256)
void gather2_kernel(const ushort* __restrict__ xw, const float* __restrict__ dinv,
                    const int* __restrict__ rowptr, const int2* __restrict__ ew,
                    const float* __restrict__ bias, ushort* __restrict__ out, int n)
{
    const int node = blockIdx.x * 4 + (threadIdx.x >> 6);
    const int lane = threadIdx.x & 63;
    if (node >= n) return;
    const float dt = dinv[node];
    int j = rowptr[node];
    const int j1 = rowptr[node + 1];

    float acc = fmaf(bf2f(xw[(size_t)node * 64 + lane]), dt * dt, bias[lane]);
    for (; j + 3 < j1; j += 4) {
        const int2 p0 = ew[j], p1 = ew[j + 1], p2 = ew[j + 2], p3 = ew[j + 3];
        const float v0 = bf2f(xw[(size_t)p0.x * 64 + lane]);
        const float v1 = bf2f(xw[(size_t)p1.x * 64 + lane]);
        const float v2 = bf2f(xw[(size_t)p2.x * 64 + lane]);
        const float v3 = bf2f(xw[(size_t)p3.x * 64 + lane]);
        acc = fmaf(v0, __int_as_float(p0.y), acc);
        acc = fmaf(v1, __int_as_float(p1.y), acc);
        acc = fmaf(v2, __int_as_float(p2.y), acc);
        acc = fmaf(v3, __int_as_float(p3.y), acc);
    }
    for (; j < j1; ++j) {
        const int2 p0 = ew[j];
        acc = fmaf(bf2f(xw[(size_t)p0.x * 64 + lane]), __int_as_float(p0.y), acc);
    }
    out[(size_t)node * 64 + lane] = f2bf(acc);
}

// ---------------------------------------------------------------------------
// logits[e] = dot(h2[a], h2[b]) over D=64 bf16. 8 lanes/edge, uint4 loads.
// ---------------------------------------------------------------------------
__global__ void score_kernel(const ushort* __restrict__ h, const int* __restrict__ ea,
                             const int* __restrict__ eb, float* __restrict__ out, int E)
{
    long long gid = (long long)blockIdx.x * blockDim.x + threadIdx.x;
    int e = (int)(gid >> 3);
    int l = (int)(gid & 7);
    if (e >= E) return;
    int a = ea[e], b = eb[e];
    uint4 ua = *(const uint4*)(h + (size_t)a * 64 + 8 * l);
    uint4 ub = *(const uint4*)(h + (size_t)b * 64 + 8 * l);
    float s;
    s  = __uint_as_float(ua.x << 16)         * __uint_as_float(ub.x << 16);
    s += __uint_as_float(ua.x & 0xFFFF0000u) * __uint_as_float(ub.x & 0xFFFF0000u);
    s += __uint_as_float(ua.y << 16)         * __uint_as_float(ub.y << 16);
    s += __uint_as_float(ua.y & 0xFFFF0000u) * __uint_as_float(ub.y & 0xFFFF0000u);
    s += __uint_as_float(ua.z << 16)         * __uint_as_float(ub.z << 16);
    s += __uint_as_float(ua.z & 0xFFFF0000u) * __uint_as_float(ub.z & 0xFFFF0000u);
    s += __uint_as_float(ua.w << 16)         * __uint_as_float(ub.w << 16);
    s += __uint_as_float(ua.w & 0xFFFF0000u) * __uint_as_float(ub.w & 0xFFFF0000u);
    s += __shfl_xor(s, 4);
    s += __shfl_xor(s, 2);
    s += __shfl_xor(s, 1);
    if (l == 0) out[e] = s;
}

extern "C" void kernel_launch(void* const* d_in, const int* in_sizes, int n_in,
                              void* d_out, int out_size, void* d_ws, size_t ws_size,
                              hipStream_t stream)
{
    const float* x              = (const float*)d_in[0];
    const int*   edge_index     = (const int*)d_in[1];
    const int*   pos_edge_index = (const int*)d_in[2];
    const float* W_init         = (const float*)d_in[3];
    const float* b_init         = (const float*)d_in[4];
    const float* W1             = (const float*)d_in[5];
    const float* b1             = (const float*)d_in[6];
    const float* W2             = (const float*)d_in[7];
    const float* b2             = (const float*)d_in[8];
    float* out = (float*)d_out;

    const int N     = in_sizes[0] / 128;   // 100000
    const int Epred = in_sizes[1] / 2;     // 200000
    const int E     = in_sizes[2] / 2;     // 500000

    const int* src = pos_edge_index;
    const int* tgt = pos_edge_index + E;
    const int* ea  = edge_index;
    const int* eb  = edge_index + Epred;

    // ---- workspace ----
    int2*   ew   = (int2*)d_ws;                      // E
    ushort* regA = (ushort*)(ew + E);                // N*128   (xw1 / xw2)
    ushort* regB = regA + (size_t)N * 128;           // N*128   (r1 / h2)
    float*  dinv = (float*)(regB + (size_t)N * 128);
    int*   counts = (int*)(dinv + N);                // N
    int*   cursor = counts + N;                      // N
    int*   rowptr = cursor + N;                      // N+2
    int*   bsum   = rowptr + N + 2;                  // 256
    ushort* WTi = (ushort*)(((uintptr_t)(bsum + 256) + 15) & ~(uintptr_t)15);  // 128*128
    ushort* WT1 = WTi + 16384;                       // 128*128
    ushort* WT2 = WT1 + 16384;                       // 64*128

    ushort* xw1 = regA;
    ushort* r1  = regB;
    ushort* xw2 = regA;                // overwrites xw1 (dead after gather1)
    ushort* h2  = regB;                // overwrites r1 (dead after gemm2)

    const int BLK = 256;
    const int nb  = (N + 1023) / 1024;
    const int gemm_grid = (N + 127) / 128;

    // ---- CSR build ----
    zero_ints_kernel<<<(2 * N + BLK - 1) / BLK, BLK, 0, stream>>>(counts, 2 * N);
    hist_kernel<<<(E + BLK - 1) / BLK, BLK, 0, stream>>>(tgt, counts, E);
    scan1_kernel<<<nb, 256, 0, stream>>>(counts, rowptr, bsum, dinv, N);
    scan2_kernel<<<1, 256, 0, stream>>>(bsum, nb);
    scan3_kernel<<<(N + BLK - 1) / BLK, BLK, 0, stream>>>(rowptr, bsum, N, E);
    scatter_kernel<<<(E + BLK - 1) / BLK, BLK, 0, stream>>>(src, tgt, dinv, rowptr, cursor, ew, E);

    // ---- weight transposes (single kernel) ----
    wtrans_all_kernel<<<160, BLK, 0, stream>>>(W_init, W1, W2, WTi, WT1, WT2);

    // ---- fused gemm0+gemm1: xw1 = bf16((x@Wi+bi)@W1) ----
    fused_gemm01_kernel<<<gemm_grid, BLK, 0, stream>>>(x, WTi, WT1, b_init, xw1, N);

    // ---- gather1: r1 = bf16(relu(agg(xw1)+self+b1)) ----
    gather1_kernel<<<(N + 3) / 4, BLK, 0, stream>>>(xw1, dinv, rowptr, ew, b1, r1, N);

    // ---- gemm2: xw2 = bf16(r1 @ W2) ----
    gemm2_kernel<<<gemm_grid, BLK, 0, stream>>>(r1, WT2, xw2, N);

    // ---- gather2: h2 = bf16(agg(xw2)+self+b2) ----
    gather2_kernel<<<(N + 3) / 4, BLK, 0, stream>>>(xw2, dinv, rowptr, ew, b2, h2, N);

    // ---- scoring ----
    score_kernel<<<((long long)Epred * 8 + BLK - 1) / BLK, BLK, 0, stream>>>(
        h2, ea, eb, out, Epred);
}

// Round 8
// 192.628 us; speedup vs baseline: 2.7235x; 1.0223x over previous
//
#include <hip/hip_runtime.h>

// ---------------------------------------------------------------------------
// GCN link-prediction pipeline, R8 (= R7 with the xw1/xw2 aliasing race fixed:
// conv1_fused gathers xw1 from ALL rows, so xw2 must live in a different
// buffer; R7 wrote xw2 over xw1 concurrently -> cross-block corruption).
//   fused01:     xw1 = bf16( (x @ W_init + b_init) @ W1 )   [h0 split-bf16 in LDS]
//   conv1_fused: xw2 = bf16( relu(gather(xw1)+self+b1) @ W2 )  [r1 lives in LDS]
//   gath2:       h2 = bf16(gather(xw2)+self+b2)
//   score:       logits[e] = dot(h2[ea], h2[eb])            [8 lanes/edge, uint4]
// MFMA GEMMs use OPERAND-SWAPPED mfma (bfrag, afrag) -> transposed C layout:
//   lane holds 4 consecutive output cols of one row -> 8B packed bf16 stores.
// ---------------------------------------------------------------------------

typedef __attribute__((ext_vector_type(8))) short short8;
typedef __attribute__((ext_vector_type(4))) float f32x4;

__device__ __forceinline__ ushort f2bf(float v) {
    unsigned u = __float_as_uint(v);
    return (ushort)((u + 0x7FFFu + ((u >> 16) & 1u)) >> 16);
}
__device__ __forceinline__ float bf2f(ushort b) {
    return __uint_as_float(((unsigned)b) << 16);
}
__device__ __forceinline__ float bflo(unsigned u) { return __uint_as_float(u << 16); }
__device__ __forceinline__ float bfhi(unsigned u) { return __uint_as_float(u & 0xFFFF0000u); }
__device__ __forceinline__ unsigned packbf(float x, float y) {
    return (unsigned)f2bf(x) | ((unsigned)f2bf(y) << 16);
}
__device__ __forceinline__ void split2(float v, ushort& h, ushort& l) {
    unsigned u = __float_as_uint(v);
    unsigned hb = (u + 0x7FFFu + ((u >> 16) & 1u)) & 0xFFFF0000u;
    h = (ushort)(hb >> 16);
    l = f2bf(v - __uint_as_float(hb));
}

// ---------------- prep: zero counts/cursor + all weight transposes ----------
__global__ void prep_kernel(const float* __restrict__ Wi, const float* __restrict__ W1,
                            const float* __restrict__ W2,
                            ushort* __restrict__ Ti, ushort* __restrict__ T1,
                            ushort* __restrict__ T2, int* __restrict__ zp, int ztot)
{
    int o = blockIdx.x * blockDim.x + threadIdx.x;
    if (o < ztot) zp[o] = 0;
    if (o < 16384) {
        int c = o >> 7, k = o & 127;
        Ti[o] = f2bf(Wi[(size_t)k * 128 + c]);
    } else if (o < 32768) {
        int p = o - 16384;
        int c = p >> 7, k = p & 127;
        T1[p] = f2bf(W1[(size_t)k * 128 + c]);
    } else if (o < 40960) {
        int p = o - 32768;
        int c = p >> 7, k = p & 127;
        T2[p] = f2bf(W2[(size_t)k * 64 + c]);
    }
}

// ---------------- CSR build ----------------
__global__ void hist_kernel(const int* __restrict__ tgt, int* __restrict__ counts, int e) {
    int i = blockIdx.x * blockDim.x + threadIdx.x;
    if (i < e) atomicAdd(&counts[tgt[i]], 1);
}
__global__ __launch_bounds__(256)
void scan1_kernel(const int* __restrict__ counts, int* __restrict__ rowptr,
                  int* __restrict__ bsum, float* __restrict__ dinv, int n)
{
    __shared__ int sdata[256];
    const int t = threadIdx.x;
    const int base = blockIdx.x * 1024 + t * 4;
    int v[4];
#pragma unroll
    for (int i = 0; i < 4; i++) v[i] = (base + i < n) ? counts[base + i] : 0;
#pragma unroll
    for (int i = 0; i < 4; i++)
        if (base + i < n) dinv[base + i] = 1.0f / sqrtf((float)(v[i] + 1));
    int tsum = v[0] + v[1] + v[2] + v[3];
    sdata[t] = tsum;
    __syncthreads();
    for (int off = 1; off < 256; off <<= 1) {
        int x = (t >= off) ? sdata[t - off] : 0;
        __syncthreads();
        if (t >= off) sdata[t] += x;
        __syncthreads();
    }
    if (t == 255) bsum[blockIdx.x] = sdata[255];
    int run = sdata[t] - tsum;
#pragma unroll
    for (int i = 0; i < 4; i++) {
        if (base + i < n) rowptr[base + i] = run;
        run += v[i];
    }
}
__global__ __launch_bounds__(256)
void scan2_kernel(int* __restrict__ bsum, int nb)
{
    __shared__ int sdata[256];
    const int t = threadIdx.x;
    int v = (t < nb) ? bsum[t] : 0;
    sdata[t] = v;
    __syncthreads();
    for (int off = 1; off < 256; off <<= 1) {
        int x = (t >= off) ? sdata[t - off] : 0;
        __syncthreads();
        if (t >= off) sdata[t] += x;
        __syncthreads();
    }
    if (t < nb) bsum[t] = sdata[t] - v;
}
__global__ void scan3_kernel(int* __restrict__ rowptr, const int* __restrict__ bsum,
                             int n, int e_total)
{
    int i = blockIdx.x * blockDim.x + threadIdx.x;
    if (i < n) rowptr[i] += bsum[i >> 10];
    if (i == 0) rowptr[n] = e_total;
}
__global__ void scatter_kernel(const int* __restrict__ src, const int* __restrict__ tgt,
                               const float* __restrict__ dinv, const int* __restrict__ rowptr,
                               int* __restrict__ cursor, int2* __restrict__ ew, int e)
{
    int i = blockIdx.x * blockDim.x + threadIdx.x;
    if (i >= e) return;
    int s = src[i], t = tgt[i];
    int p = rowptr[t] + atomicAdd(&cursor[t], 1);
    ew[p] = make_int2(s, __float_as_int(dinv[s] * dinv[t]));
}

// ---------------------------------------------------------------------------
// Fused gemm0+gemm1: xw1 = bf16((x @ Wi + bi) @ W1).  (unchanged)
// ---------------------------------------------------------------------------
__global__ __launch_bounds__(256)
void fused_gemm01_kernel(const float* __restrict__ x,
                         const ushort* __restrict__ WTi, const ushort* __restrict__ WT1,
                         const float* __restrict__ bias, ushort* __restrict__ xw1, int M)
{
    __shared__ ushort raw[36864];                       // 72 KiB
    ushort (*H0h)[128][8] = (ushort(*)[128][8])raw;
    ushort (*H0l)[128][8] = (ushort(*)[128][8])(raw + 16384);
    ushort (*Bs)[128][8]  = (ushort(*)[128][8])(raw + 32768);

    const int tid = threadIdx.x;
    const int row0 = blockIdx.x * 128;
    const int wv = tid >> 6;
    const int l  = tid & 63;
    const int lr = l & 15;
    const int lk = l >> 4;

    f32x4 acc0[8], acc1[8];
#pragma unroll
    for (int n = 0; n < 8; ++n) {
        acc0[n] = (f32x4){0.f, 0.f, 0.f, 0.f};
        acc1[n] = (f32x4){0.f, 0.f, 0.f, 0.f};
    }

    for (int kk = 0; kk < 128; kk += 32) {
        {
            const int r  = tid >> 1;
            const int kh = tid & 1;
            const int gr = row0 + r;
            float f[16];
            if (gr < M) {
                const float4* p = (const float4*)(x + (size_t)gr * 128 + kk + kh * 16);
                float4 q0 = p[0], q1 = p[1], q2 = p[2], q3 = p[3];
                f[0]=q0.x; f[1]=q0.y; f[2]=q0.z; f[3]=q0.w;
                f[4]=q1.x; f[5]=q1.y; f[6]=q1.z; f[7]=q1.w;
                f[8]=q2.x; f[9]=q2.y; f[10]=q2.z; f[11]=q2.w;
                f[12]=q3.x; f[13]=q3.y; f[14]=q3.z; f[15]=q3.w;
            } else {
#pragma unroll
                for (int j = 0; j < 16; j++) f[j] = 0.f;
            }
#pragma unroll
            for (int uu = 0; uu < 2; ++uu) {
                short8 hv, lv;
#pragma unroll
                for (int j = 0; j < 8; ++j) {
                    ushort h, lo;
                    split2(f[8 * uu + j], h, lo);
                    hv[j] = (short)h; lv[j] = (short)lo;
                }
                *(short8*)&H0h[2 * kh + uu][r][0] = hv;
                *(short8*)&H0l[2 * kh + uu][r][0] = lv;
            }
        }
        {
#pragma unroll
            for (int u = 0; u < 2; ++u) {
                const int unit = tid * 2 + u;
                const int c   = unit >> 2;
                const int kgl = unit & 3;
                *(short8*)&Bs[kgl][c][0] = *(const short8*)(WTi + (size_t)c * 128 + kk + 8 * kgl);
            }
        }
        __syncthreads();
        short8 ah0 = *(const short8*)&H0h[lk][wv * 32 + lr][0];
        short8 ah1 = *(const short8*)&H0h[lk][wv * 32 + 16 + lr][0];
        short8 al0 = *(const short8*)&H0l[lk][wv * 32 + lr][0];
        short8 al1 = *(const short8*)&H0l[lk][wv * 32 + 16 + lr][0];
#pragma unroll
        for (int n = 0; n < 8; ++n) {
            short8 bh = *(const short8*)&Bs[lk][n * 16 + lr][0];
            acc0[n] = __builtin_amdgcn_mfma_f32_16x16x32_bf16(bh, ah0, acc0[n], 0, 0, 0);
            acc1[n] = __builtin_amdgcn_mfma_f32_16x16x32_bf16(bh, ah1, acc1[n], 0, 0, 0);
            acc0[n] = __builtin_amdgcn_mfma_f32_16x16x32_bf16(bh, al0, acc0[n], 0, 0, 0);
            acc1[n] = __builtin_amdgcn_mfma_f32_16x16x32_bf16(bh, al1, acc1[n], 0, 0, 0);
        }
        __syncthreads();
    }

#pragma unroll
    for (int n = 0; n < 8; ++n) {
        const float4 b4 = *(const float4*)(bias + n * 16 + 4 * lk);
        const float bb[4] = {b4.x, b4.y, b4.z, b4.w};
        const int ks = 2 * n + (lk >> 1);
        const int jo = (lk & 1) * 4;
#pragma unroll
        for (int half = 0; half < 2; ++half) {
            const int m = wv * 32 + 16 * half + lr;
            uint2 uh, ul;
            unsigned hw[4], lw[4];
#pragma unroll
            for (int r = 0; r < 4; ++r) {
                ushort h, lo;
                split2((half ? acc1[n][r] : acc0[n][r]) + bb[r], h, lo);
                hw[r] = h; lw[r] = lo;
            }
            uh.x = hw[0] | (hw[1] << 16); uh.y = hw[2] | (hw[3] << 16);
            ul.x = lw[0] | (lw[1] << 16); ul.y = lw[2] | (lw[3] << 16);
            *(uint2*)&H0h[ks][m][jo] = uh;
            *(uint2*)&H0l[ks][m][jo] = ul;
        }
    }
    __syncthreads();

#pragma unroll
    for (int n = 0; n < 8; ++n) {
        acc0[n] = (f32x4){0.f, 0.f, 0.f, 0.f};
        acc1[n] = (f32x4){0.f, 0.f, 0.f, 0.f};
    }
    for (int kk = 0; kk < 4; ++kk) {
        {
#pragma unroll
            for (int u = 0; u < 2; ++u) {
                const int unit = tid * 2 + u;
                const int c   = unit >> 2;
                const int kgl = unit & 3;
                *(short8*)&Bs[kgl][c][0] = *(const short8*)(WT1 + (size_t)c * 128 + kk * 32 + 8 * kgl);
            }
        }
        __syncthreads();
        short8 ah0 = *(const short8*)&H0h[kk * 4 + lk][wv * 32 + lr][0];
        short8 ah1 = *(const short8*)&H0h[kk * 4 + lk][wv * 32 + 16 + lr][0];
        short8 al0 = *(const short8*)&H0l[kk * 4 + lk][wv * 32 + lr][0];
        short8 al1 = *(const short8*)&H0l[kk * 4 + lk][wv * 32 + 16 + lr][0];
#pragma unroll
        for (int n = 0; n < 8; ++n) {
            short8 bh = *(const short8*)&Bs[lk][n * 16 + lr][0];
            acc0[n] = __builtin_amdgcn_mfma_f32_16x16x32_bf16(bh, ah0, acc0[n], 0, 0, 0);
            acc1[n] = __builtin_amdgcn_mfma_f32_16x16x32_bf16(bh, ah1, acc1[n], 0, 0, 0);
            acc0[n] = __builtin_amdgcn_mfma_f32_16x16x32_bf16(bh, al0, acc0[n], 0, 0, 0);
            acc1[n] = __builtin_amdgcn_mfma_f32_16x16x32_bf16(bh, al1, acc1[n], 0, 0, 0);
        }
        __syncthreads();
    }

#pragma unroll
    for (int n = 0; n < 8; ++n) {
#pragma unroll
        for (int half = 0; half < 2; ++half) {
            const int m = row0 + wv * 32 + 16 * half + lr;
            if (m < M) {
                uint2 u;
                const f32x4 a = half ? acc1[n] : acc0[n];
                u.x = (unsigned)f2bf(a[0]) | ((unsigned)f2bf(a[1]) << 16);
                u.y = (unsigned)f2bf(a[2]) | ((unsigned)f2bf(a[3]) << 16);
                *(uint2*)(xw1 + (size_t)m * 128 + n * 16 + 4 * lk) = u;
            }
        }
    }
}

// ---------------------------------------------------------------------------
// conv1_fused: xw2 = bf16( relu(gather(xw1)+self*dinv^2+b1) @ W2 ).
// Block = 64 nodes, 4 waves. Edge descriptors staged coalesced into LDS;
// r1 built in an LDS bf16 tile in MFMA k-group layout [16][65][8]; flat
// 8-deep edge pipeline per wave (lane owns dims 2d,2d+1 -> no atomics);
// MFMA epilogue with relu folded into the A-frag load.
// NOTE: xw2 must NOT alias xw1 (cross-block gather reads) — R7's bug.
// ---------------------------------------------------------------------------
#define C1_CAP 1536

__device__ __forceinline__ void tile_add(unsigned* p, float ax, float ay) {
    unsigned old = *p;
    *p = packbf(bflo(old) + ax, bfhi(old) + ay);
}

__global__ __launch_bounds__(256)
void conv1_fused_kernel(const ushort* __restrict__ xw1, const float* __restrict__ dinv,
                        const int* __restrict__ rowptr, const int2* __restrict__ ew,
                        const float* __restrict__ b1, const ushort* __restrict__ WT2,
                        ushort* __restrict__ xw2, int N)
{
    __shared__ ushort tile[16][65][8];   // 16.25 KiB
    __shared__ int2 sew[C1_CAP];         // 12 KiB
    __shared__ int srp[65];

    const int tid  = threadIdx.x;
    const int n0   = blockIdx.x * 64;
    const int nc   = min(64, N - n0);
    const int wv   = tid >> 6;
    const int lane = tid & 63;

    if (tid <= nc) srp[tid] = rowptr[n0 + tid];
    __syncthreads();
    const int e0   = srp[0];
    const int etot = srp[nc] - e0;
    const int ecap = min(etot, C1_CAP);

    // ---- stage edges (coalesced) + pack local target id into bits 20..25 ----
    for (int i = tid; i < ecap; i += 256) {
        int2 d = ew[e0 + i];
        int idx = e0 + i;
        int lo = 0, hi = nc - 1;
        while (lo < hi) { int mid = (lo + hi + 1) >> 1; if (srp[mid] <= idx) lo = mid; else hi = mid - 1; }
        sew[i] = make_int2((d.x & 0xFFFFF) | (lo << 20), d.y);
    }

    // ---- tile init: bf16(self*dinv^2 + b1); zero pad rows ----
    const float bb0 = b1[2 * lane];
    const float bb1 = b1[2 * lane + 1];
    const int  kg = lane >> 2;
    const int  jj = (2 * lane) & 7;
    unsigned* tbase = (unsigned*)&tile[kg][0][jj];   // row stride = 4 uints
    for (int r = wv; r < 64; r += 4) {
        float vx = 0.f, vy = 0.f;
        if (r < nc) {
            unsigned u = *(const unsigned*)(xw1 + (size_t)(n0 + r) * 128 + 2 * lane);
            float dt = dinv[n0 + r];
            float cc = dt * dt;
            vx = fmaf(bflo(u), cc, bb0);
            vy = fmaf(bfhi(u), cc, bb1);
        }
        tbase[r * 4] = packbf(vx, vy);
    }
    __syncthreads();

    // ---- flat edge loop: wave wv owns nodes [16wv, min(16wv+16,nc)) ----
    const int nlo = wv * 16;
    if (nlo < nc) {
        const int nhi = min(nlo + 16, nc);
        int i = srp[nlo] - e0;
        const int iend_all = srp[nhi] - e0;
        const int iend = min(iend_all, ecap);
        float ax = 0.f, ay = 0.f;
        int cur = -1;

        for (; i + 8 <= iend; i += 8) {
            int2 d[8];
#pragma unroll
            for (int u = 0; u < 8; ++u) d[u] = sew[i + u];
            unsigned v[8];
#pragma unroll
            for (int u = 0; u < 8; ++u)
                v[u] = *(const unsigned*)(xw1 + (size_t)(((unsigned)d[u].x) & 0xFFFFFu) * 128 + 2 * lane);
#pragma unroll
            for (int u = 0; u < 8; ++u) {
                const int tg = (int)(((unsigned)d[u].x) >> 20);
                if (tg != cur) {
                    if (cur >= 0) tile_add(tbase + cur * 4, ax, ay);
                    cur = tg; ax = 0.f; ay = 0.f;
                }
                const float w = __int_as_float(d[u].y);
                ax = fmaf(bflo(v[u]), w, ax);
                ay = fmaf(bfhi(v[u]), w, ay);
            }
        }
        for (; i < iend; ++i) {
            int2 d = sew[i];
            unsigned v = *(const unsigned*)(xw1 + (size_t)(((unsigned)d.x) & 0xFFFFFu) * 128 + 2 * lane);
            const int tg = (int)(((unsigned)d.x) >> 20);
            if (tg != cur) {
                if (cur >= 0) tile_add(tbase + cur * 4, ax, ay);
                cur = tg; ax = 0.f; ay = 0.f;
            }
            const float w = __int_as_float(d.y);
            ax = fmaf(bflo(v), w, ax);
            ay = fmaf(bfhi(v), w, ay);
        }
        if (cur >= 0) tile_add(tbase + cur * 4, ax, ay);

        // ---- overflow (cold path; staged capacity exceeded) ----
        if (iend_all > ecap) {
            for (int nn = nlo; nn < nhi; ++nn) {
                int lo2 = max(srp[nn] - e0, ecap);
                int hi2 = srp[nn + 1] - e0;
                if (lo2 < hi2) {
                    ax = 0.f; ay = 0.f;
                    for (int t = lo2; t < hi2; ++t) {
                        int2 d = ew[e0 + t];
                        unsigned v = *(const unsigned*)(xw1 + (size_t)d.x * 128 + 2 * lane);
                        const float w = __int_as_float(d.y);
                        ax = fmaf(bflo(v), w, ax);
                        ay = fmaf(bfhi(v), w, ay);
                    }
                    tile_add(tbase + nn * 4, ax, ay);
                }
            }
        }
    }
    __syncthreads();

    // ---- MFMA: rows m = wv*16 + lr, relu folded into A-frag load ----
    const int lr = lane & 15;
    const int lk = lane >> 4;
    f32x4 acc[4];
#pragma unroll
    for (int n = 0; n < 4; ++n) acc[n] = (f32x4){0.f, 0.f, 0.f, 0.f};

    for (int kt = 0; kt < 4; ++kt) {
        short8 ah = *(const short8*)&tile[kt * 4 + lk][wv * 16 + lr][0];
#pragma unroll
        for (int j = 0; j < 8; ++j) {
            ushort vv = (ushort)ah[j];
            ah[j] = (short)((vv & 0x8000u) ? 0 : vv);
        }
#pragma unroll
        for (int n = 0; n < 4; ++n) {
            short8 bh = *(const short8*)(WT2 + (size_t)(n * 16 + lr) * 128 + kt * 32 + lk * 8);
            acc[n] = __builtin_amdgcn_mfma_f32_16x16x32_bf16(bh, ah, acc[n], 0, 0, 0);
        }
    }

    const int ml = wv * 16 + lr;
    if (ml < nc) {
        const size_t m = (size_t)(n0 + ml);
#pragma unroll
        for (int n = 0; n < 4; ++n) {
            uint2 u;
            u.x = (unsigned)f2bf(acc[n][0]) | ((unsigned)f2bf(acc[n][1]) << 16);
            u.y = (unsigned)f2bf(acc[n][2]) | ((unsigned)f2bf(acc[n][3]) << 16);
            *(uint2*)(xw2 + m * 64 + n * 16 + 4 * lk) = u;
        }
    }
}

// ---------------------------------------------------------------------------
// gather2: h2 = bf16(agg(xw2)+self+b2). xw: [N][64] bf16. (unchanged)
// ---------------------------------------------------------------------------
__global__ __launch_bounds__(256)
void gather2_kernel(const ushort* __restrict__ xw, const float* __restrict__ dinv,
                    const int* __restrict__ rowptr, const int2* __restrict__ ew,
                    const float* __restrict__ bias, ushort* __restrict__ out, int n)
{
    const int node = blockIdx.x * 4 + (threadIdx.x >> 6);
    const int lane = threadIdx.x & 63;
    if (node >= n) return;
    const float dt = dinv[node];
    int j = rowptr[node];
    const int j1 = rowptr[node + 1];

    float acc = fmaf(bf2f(xw[(size_t)node * 64 + lane]), dt * dt, bias[lane]);
    for (; j + 3 < j1; j += 4) {
        const int2 p0 = ew[j], p1 = ew[j + 1], p2 = ew[j + 2], p3 = ew[j + 3];
        const float v0 = bf2f(xw[(size_t)p0.x * 64 + lane]);
        const float v1 = bf2f(xw[(size_t)p1.x * 64 + lane]);
        const float v2 = bf2f(xw[(size_t)p2.x * 64 + lane]);
        const float v3 = bf2f(xw[(size_t)p3.x * 64 + lane]);
        acc = fmaf(v0, __int_as_float(p0.y), acc);
        acc = fmaf(v1, __int_as_float(p1.y), acc);
        acc = fmaf(v2, __int_as_float(p2.y), acc);
        acc = fmaf(v3, __int_as_float(p3.y), acc);
    }
    for (; j < j1; ++j) {
        const int2 p0 = ew[j];
        acc = fmaf(bf2f(xw[(size_t)p0.x * 64 + lane]), __int_as_float(p0.y), acc);
    }
    out[(size_t)node * 64 + lane] = f2bf(acc);
}

// ---------------------------------------------------------------------------
// logits[e] = dot(h2[a], h2[b]) over D=64 bf16. 8 lanes/edge, uint4 loads.
// ---------------------------------------------------------------------------
__global__ void score_kernel(const ushort* __restrict__ h, const int* __restrict__ ea,
                             const int* __restrict__ eb, float* __restrict__ out, int E)
{
    long long gid = (long long)blockIdx.x * blockDim.x + threadIdx.x;
    int e = (int)(gid >> 3);
    int l = (int)(gid & 7);
    if (e >= E) return;
    int a = ea[e], b = eb[e];
    uint4 ua = *(const uint4*)(h + (size_t)a * 64 + 8 * l);
    uint4 ub = *(const uint4*)(h + (size_t)b * 64 + 8 * l);
    float s;
    s  = __uint_as_float(ua.x << 16)         * __uint_as_float(ub.x << 16);
    s += __uint_as_float(ua.x & 0xFFFF0000u) * __uint_as_float(ub.x & 0xFFFF0000u);
    s += __uint_as_float(ua.y << 16)         * __uint_as_float(ub.y << 16);
    s += __uint_as_float(ua.y & 0xFFFF0000u) * __uint_as_float(ub.y & 0xFFFF0000u);
    s += __uint_as_float(ua.z << 16)         * __uint_as_float(ub.z << 16);
    s += __uint_as_float(ua.z & 0xFFFF0000u) * __uint_as_float(ub.z & 0xFFFF0000u);
    s += __uint_as_float(ua.w << 16)         * __uint_as_float(ub.w << 16);
    s += __uint_as_float(ua.w & 0xFFFF0000u) * __uint_as_float(ub.w & 0xFFFF0000u);
    s += __shfl_xor(s, 4);
    s += __shfl_xor(s, 2);
    s += __shfl_xor(s, 1);
    if (l == 0) out[e] = s;
}

extern "C" void kernel_launch(void* const* d_in, const int* in_sizes, int n_in,
                              void* d_out, int out_size, void* d_ws, size_t ws_size,
                              hipStream_t stream)
{
    const float* x              = (const float*)d_in[0];
    const int*   edge_index     = (const int*)d_in[1];
    const int*   pos_edge_index = (const int*)d_in[2];
    const float* W_init         = (const float*)d_in[3];
    const float* b_init         = (const float*)d_in[4];
    const float* W1             = (const float*)d_in[5];
    const float* b1             = (const float*)d_in[6];
    const float* W2             = (const float*)d_in[7];
    const float* b2             = (const float*)d_in[8];
    float* out = (float*)d_out;

    const int N     = in_sizes[0] / 128;   // 100000
    const int Epred = in_sizes[1] / 2;     // 200000
    const int E     = in_sizes[2] / 2;     // 500000

    const int* src = pos_edge_index;
    const int* tgt = pos_edge_index + E;
    const int* ea  = edge_index;
    const int* eb  = edge_index + Epred;

    // ---- workspace ----
    int2*   ew   = (int2*)d_ws;                      // E
    ushort* regA = (ushort*)(ew + E);                // N*128   (xw1 — stays live through conv1_fused)
    ushort* regB = regA + (size_t)N * 128;           // N*128   (= two N*64 planes: xw2, h2)
    float*  dinv = (float*)(regB + (size_t)N * 128);
    int*   counts = (int*)(dinv + N);                // N
    int*   cursor = counts + N;                      // N
    int*   rowptr = cursor + N;                      // N+2
    int*   bsum   = rowptr + N + 2;                  // 256
    ushort* WTi = (ushort*)(((uintptr_t)(bsum + 256) + 15) & ~(uintptr_t)15);  // 128*128
    ushort* WT1 = WTi + 16384;                       // 128*128
    ushort* WT2 = WT1 + 16384;                       // 64*128

    ushort* xw1 = regA;
    ushort* xw2 = regB;                      // FIX: distinct from xw1 (R7 race)
    ushort* h2  = regB + (size_t)N * 64;     // distinct from xw2 (gather2 reads xw2)

    const int BLK = 256;
    const int nb  = (N + 1023) / 1024;

    // ---- prep: zero counts+cursor, transpose all weights ----
    prep_kernel<<<(2 * N + BLK - 1) / BLK, BLK, 0, stream>>>(
        W_init, W1, W2, WTi, WT1, WT2, counts, 2 * N);

    // ---- CSR build ----
    hist_kernel<<<(E + BLK - 1) / BLK, BLK, 0, stream>>>(tgt, counts, E);
    scan1_kernel<<<nb, 256, 0, stream>>>(counts, rowptr, bsum, dinv, N);
    scan2_kernel<<<1, 256, 0, stream>>>(bsum, nb);
    scan3_kernel<<<(N + BLK - 1) / BLK, BLK, 0, stream>>>(rowptr, bsum, N, E);
    scatter_kernel<<<(E + BLK - 1) / BLK, BLK, 0, stream>>>(src, tgt, dinv, rowptr, cursor, ew, E);

    // ---- fused gemm0+gemm1: xw1 = bf16((x@Wi+bi)@W1) ----
    fused_gemm01_kernel<<<(N + 127) / 128, BLK, 0, stream>>>(x, WTi, WT1, b_init, xw1, N);

    // ---- conv1_fused: xw2 = bf16(relu(agg(xw1)+self+b1) @ W2) ----
    conv1_fused_kernel<<<(N + 63) / 64, BLK, 0, stream>>>(
        xw1, dinv, rowptr, ew, b1, WT2, xw2, N);

    // ---- gather2: h2 = bf16(agg(xw2)+self+b2) ----
    gather2_kernel<<<(N + 3) / 4, BLK, 0, stream>>>(xw2, dinv, rowptr, ew, b2, h2, N);

    // ---- scoring ----
    score_kernel<<<((long long)Epred * 8 + BLK - 1) / BLK, BLK, 0, stream>>>(
        h2, ea, eb, out, Epred);
}